// Round 5
// baseline (2975.905 us; speedup 1.0000x reference)
//
#include <hip/hip_runtime.h>
#include <hip/hip_fp16.h>

#define EPS 1e-5f
#define SCAN_CHUNK 1024   // elements per block in the parallel scan

// ---------------- graph prep ----------------

__global__ __launch_bounds__(256) void hist_kernel(const int* __restrict__ ei, int E, int* __restrict__ count) {
    int e = blockIdx.x * blockDim.x + threadIdx.x;
    if (e < E) atomicAdd(&count[ei[E + e]], 1);   // col = target
}

__global__ __launch_bounds__(256) void dinv_kernel(const int* __restrict__ count, float* __restrict__ dinv, int n) {
    int i = blockIdx.x * blockDim.x + threadIdx.x;
    if (i < n) dinv[i] = rsqrtf((float)(count[i] + 1));   // +1 self-loop
}

// pass 1: per-block (1024 elems) local exclusive scan into rowptr, block total into bsum
__global__ __launch_bounds__(256) void scan_pass1(const int* __restrict__ count, int* __restrict__ rowptr,
                                                  int* __restrict__ bsum, int n) {
    __shared__ int ssum[256];
    int t = threadIdx.x;
    int base = blockIdx.x * SCAN_CHUNK + t * 4;
    int v0 = 0, v1 = 0, v2 = 0, v3 = 0;
    if (base + 3 < n) {
        int4 vv = *(const int4*)(count + base);
        v0 = vv.x; v1 = vv.y; v2 = vv.z; v3 = vv.w;
    } else {
        if (base + 0 < n) v0 = count[base + 0];
        if (base + 1 < n) v1 = count[base + 1];
        if (base + 2 < n) v2 = count[base + 2];
        if (base + 3 < n) v3 = count[base + 3];
    }
    int s = v0 + v1 + v2 + v3;
    ssum[t] = s;
    __syncthreads();
    for (int off = 1; off < 256; off <<= 1) {
        int u = (t >= off) ? ssum[t - off] : 0;
        __syncthreads();
        ssum[t] += u;
        __syncthreads();
    }
    int excl = ssum[t] - s;
    int p0 = excl, p1 = excl + v0, p2 = excl + v0 + v1, p3 = excl + v0 + v1 + v2;
    if (base + 3 < n) {
        *(int4*)(rowptr + base) = make_int4(p0, p1, p2, p3);
    } else {
        if (base + 0 < n) rowptr[base + 0] = p0;
        if (base + 1 < n) rowptr[base + 1] = p1;
        if (base + 2 < n) rowptr[base + 2] = p2;
        if (base + 3 < n) rowptr[base + 3] = p3;
    }
    if (t == 255) bsum[blockIdx.x] = ssum[255];
}

// pass 2: scan block sums (nb <= 1024), write exclusive block offsets + rowptr[n]
__global__ __launch_bounds__(1024) void scan_pass2(const int* __restrict__ bsum, int* __restrict__ boffs,
                                                   int* __restrict__ rowptr, int nb, int n) {
    __shared__ int s[1024];
    int t = threadIdx.x;
    int v = (t < nb) ? bsum[t] : 0;
    s[t] = v;
    __syncthreads();
    for (int off = 1; off < 1024; off <<= 1) {
        int u = (t >= off) ? s[t - off] : 0;
        __syncthreads();
        s[t] += u;
        __syncthreads();
    }
    if (t < nb) boffs[t] = s[t] - v;
    if (t == 1023) rowptr[n] = s[1023];
}

// pass 3: add block offsets, materialize cursor
__global__ __launch_bounds__(256) void scan_pass3(int* __restrict__ rowptr, int* __restrict__ cursor,
                                                  const int* __restrict__ boffs, int n) {
    int t = threadIdx.x;
    int base = blockIdx.x * SCAN_CHUNK + t * 4;
    int off = boffs[blockIdx.x];
    if (base + 3 < n) {
        int4 v = *(int4*)(rowptr + base);
        v.x += off; v.y += off; v.z += off; v.w += off;
        *(int4*)(rowptr + base) = v;
        *(int4*)(cursor + base) = v;
    } else {
        for (int j = 0; j < 4; ++j)
            if (base + j < n) { int v = rowptr[base + j] + off; rowptr[base + j] = v; cursor[base + j] = v; }
    }
}

// scatter: CSR entry = (source index, norm weight dinv[src]*dinv[dst]) packed as int2
__global__ __launch_bounds__(256) void scatter_kernel(const int* __restrict__ ei, int E,
                                                      const float* __restrict__ dinv,
                                                      int* __restrict__ cursor, int2* __restrict__ csrw) {
    int e = blockIdx.x * blockDim.x + threadIdx.x;
    if (e < E) {
        int r = ei[e];          // source
        int c = ei[E + e];      // target
        int pos = atomicAdd(&cursor[c], 1);
        float w = dinv[r] * dinv[c];
        csrw[pos] = make_int2(r, __float_as_int(w));
    }
}

// ---------------- dense GEMM: [n,K](f32) @ [K,64](f32) -> [n,64] (f16) ----------------
// 16 rows/block, 4 rows/thread (4 acc). k-step-4: A via wave-uniform broadcast
// ds_read_b128 (16 B/instr, cheap), W via stride-1 b32. __launch_bounds__(256,4)
// caps VGPR <= 128 (R3's 8-row variant hit 256 VGPR / 10% occupancy).

template <int K>
__global__ __launch_bounds__(256, 4) void gemm_kernel(const float* __restrict__ A, const float* __restrict__ W,
                                                      __half* __restrict__ out, int n) {
    __shared__ float Wl[K * 64];
    __shared__ float Al[16 * K];
    int tid = threadIdx.x;
    for (int f = tid; f < K * 64; f += 256) Wl[f] = W[f];
    int row0 = blockIdx.x * 16;
    const float* Ab = A + (size_t)row0 * K;
    int limit = (n - row0) * K; if (limit > 16 * K) limit = 16 * K;
    for (int f = tid * 4; f < 16 * K; f += 1024) {
        float4 v = make_float4(0.f, 0.f, 0.f, 0.f);
        if (f + 3 < limit) {
            v = *(const float4*)(Ab + f);
        } else {
            if (f + 0 < limit) v.x = Ab[f + 0];
            if (f + 1 < limit) v.y = Ab[f + 1];
            if (f + 2 < limit) v.z = Ab[f + 2];
            if (f + 3 < limit) v.w = Ab[f + 3];
        }
        *(float4*)(Al + f) = v;
    }
    __syncthreads();

    int col = tid & 63, rq = tid >> 6;
    float acc0 = 0.f, acc1 = 0.f, acc2 = 0.f, acc3 = 0.f;
    const float* Ar = Al + (rq * 4) * K;
    for (int k = 0; k < K; k += 4) {
        float w0 = Wl[(k + 0) * 64 + col];
        float w1 = Wl[(k + 1) * 64 + col];
        float w2 = Wl[(k + 2) * 64 + col];
        float w3 = Wl[(k + 3) * 64 + col];
        float4 a0 = *(const float4*)(Ar + 0 * K + k);
        float4 a1 = *(const float4*)(Ar + 1 * K + k);
        float4 a2 = *(const float4*)(Ar + 2 * K + k);
        float4 a3 = *(const float4*)(Ar + 3 * K + k);
        acc0 += a0.x * w0 + a0.y * w1 + a0.z * w2 + a0.w * w3;
        acc1 += a1.x * w0 + a1.y * w1 + a1.z * w2 + a1.w * w3;
        acc2 += a2.x * w0 + a2.y * w1 + a2.z * w2 + a2.w * w3;
        acc3 += a3.x * w0 + a3.y * w1 + a3.z * w2 + a3.w * w3;
    }
    int r0 = row0 + rq * 4;
    if (r0 + 0 < n) out[(size_t)(r0 + 0) * 64 + col] = __float2half(acc0);
    if (r0 + 1 < n) out[(size_t)(r0 + 1) * 64 + col] = __float2half(acc1);
    if (r0 + 2 < n) out[(size_t)(r0 + 2) * 64 + col] = __float2half(acc2);
    if (r0 + 3 < n) out[(size_t)(r0 + 3) * 64 + col] = __float2half(acc3);
}

// ---------------- aggregation + bias + BN(eval) + ReLU (+classifier) ----------------
// Wave = 2 groups x 32 lanes; lane owns a half2 feature pair; each gather
// instruction fetches 2 different rows (one per group) -> 2x cache lines in
// flight per instruction slot. Unroll 4 -> 8 rows outstanding per wave.

template <bool FUSE_CLS>
__global__ __launch_bounds__(256) void agg_kernel(const __half* __restrict__ t, const float* __restrict__ dinv,
                                                  const int* __restrict__ rowptr, const int2* __restrict__ csrw,
                                                  const float* __restrict__ bias, const float* __restrict__ gamma,
                                                  const float* __restrict__ beta, const float* __restrict__ mean,
                                                  const float* __restrict__ var, float* __restrict__ out,
                                                  const float* __restrict__ cls_w, const float* __restrict__ cls_b,
                                                  int n) {
    int wave = threadIdx.x >> 6;
    int lane = threadIdx.x & 63;
    int g = lane >> 5;          // edge group 0/1
    int fl = lane & 31;         // feature-pair index (features 2*fl, 2*fl+1)
    int i = blockIdx.x * (blockDim.x >> 6) + wave;
    if (i >= n) return;

    const half2* t2 = (const half2*)t;
    float2 acc = make_float2(0.f, 0.f);

    if (g == 0) {   // self-loop counted once
        float di = dinv[i];
        float2 v = __half22float2(t2[(size_t)i * 32 + fl]);
        acc.x = di * di * v.x;
        acc.y = di * di * v.y;
    }

    int e0 = rowptr[i], e1 = rowptr[i + 1];
    int e = e0;
    for (; e + 8 <= e1; e += 8) {
        int2 a0 = csrw[e + 0 + g];
        int2 a1 = csrw[e + 2 + g];
        int2 a2 = csrw[e + 4 + g];
        int2 a3 = csrw[e + 6 + g];
        float2 v0 = __half22float2(t2[(size_t)a0.x * 32 + fl]);
        float2 v1 = __half22float2(t2[(size_t)a1.x * 32 + fl]);
        float2 v2 = __half22float2(t2[(size_t)a2.x * 32 + fl]);
        float2 v3 = __half22float2(t2[(size_t)a3.x * 32 + fl]);
        float w0 = __int_as_float(a0.y), w1 = __int_as_float(a1.y);
        float w2 = __int_as_float(a2.y), w3 = __int_as_float(a3.y);
        acc.x += w0 * v0.x + w1 * v1.x + w2 * v2.x + w3 * v3.x;
        acc.y += w0 * v0.y + w1 * v1.y + w2 * v2.y + w3 * v3.y;
    }
    for (; e + 2 <= e1; e += 2) {
        int2 a = csrw[e + g];
        float2 v = __half22float2(t2[(size_t)a.x * 32 + fl]);
        float w = __int_as_float(a.y);
        acc.x += w * v.x;
        acc.y += w * v.y;
    }
    if (e < e1 && g == 0) {     // odd last edge
        int2 a = csrw[e];
        float2 v = __half22float2(t2[(size_t)a.x * 32 + fl]);
        float w = __int_as_float(a.y);
        acc.x += w * v.x;
        acc.y += w * v.y;
    }

    // combine the two groups
    acc.x += __shfl_xor(acc.x, 32);
    acc.y += __shfl_xor(acc.y, 32);

    // bias + BN(eval) + ReLU on the feature pair
    float2 bb = ((const float2*)bias)[fl];
    float2 gg = ((const float2*)gamma)[fl];
    float2 be = ((const float2*)beta)[fl];
    float2 mm = ((const float2*)mean)[fl];
    float2 vv = ((const float2*)var)[fl];
    float sx = gg.x * rsqrtf(vv.x + EPS);
    float sy = gg.y * rsqrtf(vv.y + EPS);
    float rx = fmaxf((acc.x + bb.x - mm.x) * sx + be.x, 0.f);
    float ry = fmaxf((acc.y + bb.y - mm.y) * sy + be.y, 0.f);

    if (!FUSE_CLS) {
        if (g == 0) ((float2*)out)[(size_t)i * 32 + fl] = make_float2(rx, ry);
    } else {
        // cls_w layout [64][2]; float4 at fl covers features 2fl,2fl+1
        float4 cw = ((const float4*)cls_w)[fl];
        float c0 = rx * cw.x + ry * cw.z;
        float c1 = rx * cw.y + ry * cw.w;
        for (int off = 16; off > 0; off >>= 1) {
            c0 += __shfl_xor(c0, off);
            c1 += __shfl_xor(c1, off);
        }
        if (lane == 0) {
            out[(size_t)i * 2 + 0] = c0 + cls_b[0];
            out[(size_t)i * 2 + 1] = c1 + cls_b[1];
        }
    }
}

// ---------------- launch ----------------

extern "C" void kernel_launch(void* const* d_in, const int* in_sizes, int n_in,
                              void* d_out, int out_size, void* d_ws, size_t ws_size,
                              hipStream_t stream) {
    const float* x      = (const float*)d_in[0];
    const int*   ei     = (const int*)d_in[1];
    const float* w0     = (const float*)d_in[2];
    const float* w1     = (const float*)d_in[3];
    const float* w2     = (const float*)d_in[4];
    const float* biases = (const float*)d_in[5];
    const float* gamma  = (const float*)d_in[6];
    const float* beta   = (const float*)d_in[7];
    const float* rmean  = (const float*)d_in[8];
    const float* rvar   = (const float*)d_in[9];
    const float* cls_w  = (const float*)d_in[10];
    const float* cls_b  = (const float*)d_in[11];
    float* out = (float*)d_out;

    const int IN = 128, H = 64;
    const int N = in_sizes[0] / IN;   // 100000
    const int E = in_sizes[1] / 2;    // 1200000

    char* p = (char*)d_ws;
    auto carve = [&](size_t bytes) { void* q = (void*)p; p += (bytes + 255) & ~(size_t)255; return q; };
    float* dinv   = (float*)carve((size_t)N * 4);
    int*   count  = (int*)carve((size_t)N * 4);
    int*   rowptr = (int*)carve((size_t)(N + 1) * 4);
    int*   cursor = (int*)carve((size_t)N * 4);
    int2*  csrw   = (int2*)carve((size_t)E * 8);
    int*   bsum   = (int*)carve((size_t)1024 * 4);
    int*   boffs  = (int*)carve((size_t)1024 * 4);
    __half* tbuf  = (__half*)carve((size_t)N * H * 2);
    float* hbuf   = (float*)carve((size_t)N * H * 4);

    int nb = (N + SCAN_CHUNK - 1) / SCAN_CHUNK;   // 98 for N=100000

    hipMemsetAsync(count, 0, (size_t)N * 4, stream);
    hist_kernel<<<(E + 255) / 256, 256, 0, stream>>>(ei, E, count);
    dinv_kernel<<<(N + 255) / 256, 256, 0, stream>>>(count, dinv, N);
    scan_pass1<<<nb, 256, 0, stream>>>(count, rowptr, bsum, N);
    scan_pass2<<<1, 1024, 0, stream>>>(bsum, boffs, rowptr, nb, N);
    scan_pass3<<<nb, 256, 0, stream>>>(rowptr, cursor, boffs, N);
    scatter_kernel<<<(E + 255) / 256, 256, 0, stream>>>(ei, E, dinv, cursor, csrw);

    int gemm_grid = (N + 15) / 16;
    int agg_grid  = (N + 3) / 4;

    // layer 0
    gemm_kernel<128><<<gemm_grid, 256, 0, stream>>>(x, w0, tbuf, N);
    agg_kernel<false><<<agg_grid, 256, 0, stream>>>(tbuf, dinv, rowptr, csrw,
        biases + 0, gamma + 0, beta + 0, rmean + 0, rvar + 0, hbuf, nullptr, nullptr, N);
    // layer 1
    gemm_kernel<64><<<gemm_grid, 256, 0, stream>>>(hbuf, w1, tbuf, N);
    agg_kernel<false><<<agg_grid, 256, 0, stream>>>(tbuf, dinv, rowptr, csrw,
        biases + H, gamma + H, beta + H, rmean + H, rvar + H, hbuf, nullptr, nullptr, N);
    // layer 2 + classifier
    gemm_kernel<64><<<gemm_grid, 256, 0, stream>>>(hbuf, w2, tbuf, N);
    agg_kernel<true><<<agg_grid, 256, 0, stream>>>(tbuf, dinv, rowptr, csrw,
        biases + 2 * H, gamma + 2 * H, beta + 2 * H, rmean + 2 * H, rvar + 2 * H, out, cls_w, cls_b, N);
}

// Round 6
// 516.173 us; speedup vs baseline: 5.7653x; 5.7653x over previous
//
#include <hip/hip_runtime.h>
#include <hip/hip_fp16.h>

#define EPS 1e-5f
#define SCAN_CHUNK 1024   // elements per block in the parallel scan

// ---------------- graph prep ----------------

__global__ __launch_bounds__(256) void hist_kernel(const int* __restrict__ ei, int E, int* __restrict__ count) {
    int e = blockIdx.x * blockDim.x + threadIdx.x;
    if (e < E) atomicAdd(&count[ei[E + e]], 1);   // col = target
}

__global__ __launch_bounds__(256) void dinv_kernel(const int* __restrict__ count, float* __restrict__ dinv, int n) {
    int i = blockIdx.x * blockDim.x + threadIdx.x;
    if (i < n) dinv[i] = rsqrtf((float)(count[i] + 1));   // +1 self-loop
}

// pass 1: per-block (1024 elems) local exclusive scan into rowptr, block total into bsum
__global__ __launch_bounds__(256) void scan_pass1(const int* __restrict__ count, int* __restrict__ rowptr,
                                                  int* __restrict__ bsum, int n) {
    __shared__ int ssum[256];
    int t = threadIdx.x;
    int base = blockIdx.x * SCAN_CHUNK + t * 4;
    int v0 = 0, v1 = 0, v2 = 0, v3 = 0;
    if (base + 3 < n) {
        int4 vv = *(const int4*)(count + base);
        v0 = vv.x; v1 = vv.y; v2 = vv.z; v3 = vv.w;
    } else {
        if (base + 0 < n) v0 = count[base + 0];
        if (base + 1 < n) v1 = count[base + 1];
        if (base + 2 < n) v2 = count[base + 2];
        if (base + 3 < n) v3 = count[base + 3];
    }
    int s = v0 + v1 + v2 + v3;
    ssum[t] = s;
    __syncthreads();
    for (int off = 1; off < 256; off <<= 1) {
        int u = (t >= off) ? ssum[t - off] : 0;
        __syncthreads();
        ssum[t] += u;
        __syncthreads();
    }
    int excl = ssum[t] - s;
    int p0 = excl, p1 = excl + v0, p2 = excl + v0 + v1, p3 = excl + v0 + v1 + v2;
    if (base + 3 < n) {
        *(int4*)(rowptr + base) = make_int4(p0, p1, p2, p3);
    } else {
        if (base + 0 < n) rowptr[base + 0] = p0;
        if (base + 1 < n) rowptr[base + 1] = p1;
        if (base + 2 < n) rowptr[base + 2] = p2;
        if (base + 3 < n) rowptr[base + 3] = p3;
    }
    if (t == 255) bsum[blockIdx.x] = ssum[255];
}

// pass 2: scan block sums (nb <= 1024), write exclusive block offsets + rowptr[n]
__global__ __launch_bounds__(1024) void scan_pass2(const int* __restrict__ bsum, int* __restrict__ boffs,
                                                   int* __restrict__ rowptr, int nb, int n) {
    __shared__ int s[1024];
    int t = threadIdx.x;
    int v = (t < nb) ? bsum[t] : 0;
    s[t] = v;
    __syncthreads();
    for (int off = 1; off < 1024; off <<= 1) {
        int u = (t >= off) ? s[t - off] : 0;
        __syncthreads();
        s[t] += u;
        __syncthreads();
    }
    if (t < nb) boffs[t] = s[t] - v;
    if (t == 1023) rowptr[n] = s[1023];
}

// pass 3: add block offsets, materialize cursor
__global__ __launch_bounds__(256) void scan_pass3(int* __restrict__ rowptr, int* __restrict__ cursor,
                                                  const int* __restrict__ boffs, int n) {
    int t = threadIdx.x;
    int base = blockIdx.x * SCAN_CHUNK + t * 4;
    int off = boffs[blockIdx.x];
    if (base + 3 < n) {
        int4 v = *(int4*)(rowptr + base);
        v.x += off; v.y += off; v.z += off; v.w += off;
        *(int4*)(rowptr + base) = v;
        *(int4*)(cursor + base) = v;
    } else {
        for (int j = 0; j < 4; ++j)
            if (base + j < n) { int v = rowptr[base + j] + off; rowptr[base + j] = v; cursor[base + j] = v; }
    }
}

// scatter: CSR entry = (source index, norm weight dinv[src]*dinv[dst]) packed as int2
__global__ __launch_bounds__(256) void scatter_kernel(const int* __restrict__ ei, int E,
                                                      const float* __restrict__ dinv,
                                                      int* __restrict__ cursor, int2* __restrict__ csrw) {
    int e = blockIdx.x * blockDim.x + threadIdx.x;
    if (e < E) {
        int r = ei[e];          // source
        int c = ei[E + e];      // target
        int pos = atomicAdd(&cursor[c], 1);
        float w = dinv[r] * dinv[c];
        csrw[pos] = make_int2(r, __float_as_int(w));
    }
}

// ---------------- dense GEMM: [n,K](f32) @ [K,64](f32) -> [n,64] (f16) ----------------
// EXACT R2 structure (measured 69 us @ K=128, VGPR 52, no spill). Scalar LDS
// reads + "#pragma unroll 8". DO NOT fully unroll or add float4 LDS reads with
// a min-occupancy launch_bounds: LLVM pipelines the unrolled loop and spills
// to scratch (R4: 2 GB FETCH / 4 GB WRITE per dispatch, 1.8 ms).

template <int K>
__global__ __launch_bounds__(256) void gemm_kernel(const float* __restrict__ A, const float* __restrict__ W,
                                                   __half* __restrict__ out, int n) {
    __shared__ float Wl[K * 64];
    __shared__ float Al[16 * K];
    int tid = threadIdx.x;
    for (int f = tid; f < K * 64; f += 256) Wl[f] = W[f];
    int row0 = blockIdx.x * 16;
    const float* Ab = A + (size_t)row0 * K;
    int limit = (n - row0) * K; if (limit > 16 * K) limit = 16 * K;
    for (int f = tid; f < 16 * K; f += 256) Al[f] = (f < limit) ? Ab[f] : 0.f;
    __syncthreads();

    int col = tid & 63, rq = tid >> 6;
    float acc0 = 0.f, acc1 = 0.f, acc2 = 0.f, acc3 = 0.f;
#pragma unroll 8
    for (int k = 0; k < K; ++k) {
        float wv = Wl[k * 64 + col];
        acc0 += Al[(rq * 4 + 0) * K + k] * wv;
        acc1 += Al[(rq * 4 + 1) * K + k] * wv;
        acc2 += Al[(rq * 4 + 2) * K + k] * wv;
        acc3 += Al[(rq * 4 + 3) * K + k] * wv;
    }
    int r = row0 + rq * 4;
    if (r + 0 < n) out[(size_t)(r + 0) * 64 + col] = __float2half(acc0);
    if (r + 1 < n) out[(size_t)(r + 1) * 64 + col] = __float2half(acc1);
    if (r + 2 < n) out[(size_t)(r + 2) * 64 + col] = __float2half(acc2);
    if (r + 3 < n) out[(size_t)(r + 3) * 64 + col] = __float2half(acc3);
}

// ---------------- aggregation + bias + BN(eval) + ReLU (+classifier) ----------------
// Wave = 2 groups x 32 lanes; lane owns a half2 feature pair; each gather
// instruction fetches 2 different rows (one per group) -> 2x cache lines in
// flight per instruction slot. Unroll 4 -> 8 rows outstanding per wave.

template <bool FUSE_CLS>
__global__ __launch_bounds__(256) void agg_kernel(const __half* __restrict__ t, const float* __restrict__ dinv,
                                                  const int* __restrict__ rowptr, const int2* __restrict__ csrw,
                                                  const float* __restrict__ bias, const float* __restrict__ gamma,
                                                  const float* __restrict__ beta, const float* __restrict__ mean,
                                                  const float* __restrict__ var, float* __restrict__ out,
                                                  const float* __restrict__ cls_w, const float* __restrict__ cls_b,
                                                  int n) {
    int wave = threadIdx.x >> 6;
    int lane = threadIdx.x & 63;
    int g = lane >> 5;          // edge group 0/1
    int fl = lane & 31;         // feature-pair index (features 2*fl, 2*fl+1)
    int i = blockIdx.x * (blockDim.x >> 6) + wave;
    if (i >= n) return;

    const half2* t2 = (const half2*)t;
    float2 acc = make_float2(0.f, 0.f);

    if (g == 0) {   // self-loop counted once
        float di = dinv[i];
        float2 v = __half22float2(t2[(size_t)i * 32 + fl]);
        acc.x = di * di * v.x;
        acc.y = di * di * v.y;
    }

    int e0 = rowptr[i], e1 = rowptr[i + 1];
    int e = e0;
    for (; e + 8 <= e1; e += 8) {
        int2 a0 = csrw[e + 0 + g];
        int2 a1 = csrw[e + 2 + g];
        int2 a2 = csrw[e + 4 + g];
        int2 a3 = csrw[e + 6 + g];
        float2 v0 = __half22float2(t2[(size_t)a0.x * 32 + fl]);
        float2 v1 = __half22float2(t2[(size_t)a1.x * 32 + fl]);
        float2 v2 = __half22float2(t2[(size_t)a2.x * 32 + fl]);
        float2 v3 = __half22float2(t2[(size_t)a3.x * 32 + fl]);
        float w0 = __int_as_float(a0.y), w1 = __int_as_float(a1.y);
        float w2 = __int_as_float(a2.y), w3 = __int_as_float(a3.y);
        acc.x += w0 * v0.x + w1 * v1.x + w2 * v2.x + w3 * v3.x;
        acc.y += w0 * v0.y + w1 * v1.y + w2 * v2.y + w3 * v3.y;
    }
    for (; e + 2 <= e1; e += 2) {
        int2 a = csrw[e + g];
        float2 v = __half22float2(t2[(size_t)a.x * 32 + fl]);
        float w = __int_as_float(a.y);
        acc.x += w * v.x;
        acc.y += w * v.y;
    }
    if (e < e1 && g == 0) {     // odd last edge
        int2 a = csrw[e];
        float2 v = __half22float2(t2[(size_t)a.x * 32 + fl]);
        float w = __int_as_float(a.y);
        acc.x += w * v.x;
        acc.y += w * v.y;
    }

    // combine the two groups
    acc.x += __shfl_xor(acc.x, 32);
    acc.y += __shfl_xor(acc.y, 32);

    // bias + BN(eval) + ReLU on the feature pair
    float2 bb = ((const float2*)bias)[fl];
    float2 gg = ((const float2*)gamma)[fl];
    float2 be = ((const float2*)beta)[fl];
    float2 mm = ((const float2*)mean)[fl];
    float2 vv = ((const float2*)var)[fl];
    float sx = gg.x * rsqrtf(vv.x + EPS);
    float sy = gg.y * rsqrtf(vv.y + EPS);
    float rx = fmaxf((acc.x + bb.x - mm.x) * sx + be.x, 0.f);
    float ry = fmaxf((acc.y + bb.y - mm.y) * sy + be.y, 0.f);

    if (!FUSE_CLS) {
        if (g == 0) ((float2*)out)[(size_t)i * 32 + fl] = make_float2(rx, ry);
    } else {
        // cls_w layout [64][2]; float4 at fl covers features 2fl,2fl+1
        float4 cw = ((const float4*)cls_w)[fl];
        float c0 = rx * cw.x + ry * cw.z;
        float c1 = rx * cw.y + ry * cw.w;
        for (int off = 16; off > 0; off >>= 1) {
            c0 += __shfl_xor(c0, off);
            c1 += __shfl_xor(c1, off);
        }
        if (lane == 0) {
            out[(size_t)i * 2 + 0] = c0 + cls_b[0];
            out[(size_t)i * 2 + 1] = c1 + cls_b[1];
        }
    }
}

// ---------------- launch ----------------

extern "C" void kernel_launch(void* const* d_in, const int* in_sizes, int n_in,
                              void* d_out, int out_size, void* d_ws, size_t ws_size,
                              hipStream_t stream) {
    const float* x      = (const float*)d_in[0];
    const int*   ei     = (const int*)d_in[1];
    const float* w0     = (const float*)d_in[2];
    const float* w1     = (const float*)d_in[3];
    const float* w2     = (const float*)d_in[4];
    const float* biases = (const float*)d_in[5];
    const float* gamma  = (const float*)d_in[6];
    const float* beta   = (const float*)d_in[7];
    const float* rmean  = (const float*)d_in[8];
    const float* rvar   = (const float*)d_in[9];
    const float* cls_w  = (const float*)d_in[10];
    const float* cls_b  = (const float*)d_in[11];
    float* out = (float*)d_out;

    const int IN = 128, H = 64;
    const int N = in_sizes[0] / IN;   // 100000
    const int E = in_sizes[1] / 2;    // 1200000

    char* p = (char*)d_ws;
    auto carve = [&](size_t bytes) { void* q = (void*)p; p += (bytes + 255) & ~(size_t)255; return q; };
    float* dinv   = (float*)carve((size_t)N * 4);
    int*   count  = (int*)carve((size_t)N * 4);
    int*   rowptr = (int*)carve((size_t)(N + 1) * 4);
    int*   cursor = (int*)carve((size_t)N * 4);
    int2*  csrw   = (int2*)carve((size_t)E * 8);
    int*   bsum   = (int*)carve((size_t)1024 * 4);
    int*   boffs  = (int*)carve((size_t)1024 * 4);
    __half* tbuf  = (__half*)carve((size_t)N * H * 2);
    float* hbuf   = (float*)carve((size_t)N * H * 4);

    int nb = (N + SCAN_CHUNK - 1) / SCAN_CHUNK;   // 98 for N=100000

    hipMemsetAsync(count, 0, (size_t)N * 4, stream);
    hist_kernel<<<(E + 255) / 256, 256, 0, stream>>>(ei, E, count);
    dinv_kernel<<<(N + 255) / 256, 256, 0, stream>>>(count, dinv, N);
    scan_pass1<<<nb, 256, 0, stream>>>(count, rowptr, bsum, N);
    scan_pass2<<<1, 1024, 0, stream>>>(bsum, boffs, rowptr, nb, N);
    scan_pass3<<<nb, 256, 0, stream>>>(rowptr, cursor, boffs, N);
    scatter_kernel<<<(E + 255) / 256, 256, 0, stream>>>(ei, E, dinv, cursor, csrw);

    int gemm_grid = (N + 15) / 16;
    int agg_grid  = (N + 3) / 4;

    // layer 0
    gemm_kernel<128><<<gemm_grid, 256, 0, stream>>>(x, w0, tbuf, N);
    agg_kernel<false><<<agg_grid, 256, 0, stream>>>(tbuf, dinv, rowptr, csrw,
        biases + 0, gamma + 0, beta + 0, rmean + 0, rvar + 0, hbuf, nullptr, nullptr, N);
    // layer 1
    gemm_kernel<64><<<gemm_grid, 256, 0, stream>>>(hbuf, w1, tbuf, N);
    agg_kernel<false><<<agg_grid, 256, 0, stream>>>(tbuf, dinv, rowptr, csrw,
        biases + H, gamma + H, beta + H, rmean + H, rvar + H, hbuf, nullptr, nullptr, N);
    // layer 2 + classifier
    gemm_kernel<64><<<gemm_grid, 256, 0, stream>>>(hbuf, w2, tbuf, N);
    agg_kernel<true><<<agg_grid, 256, 0, stream>>>(tbuf, dinv, rowptr, csrw,
        biases + 2 * H, gamma + 2 * H, beta + 2 * H, rmean + 2 * H, rvar + 2 * H, out, cls_w, cls_b, N);
}

// Round 7
// 444.261 us; speedup vs baseline: 6.6985x; 1.1619x over previous
//
#include <hip/hip_runtime.h>
#include <hip/hip_fp16.h>

#define EPS 1e-5f
#define SCAN_CHUNK 1024   // elements per block in the parallel scan

typedef _Float16 half8 __attribute__((ext_vector_type(8)));
typedef float floatx4 __attribute__((ext_vector_type(4)));

// ---------------- graph prep ----------------

__global__ __launch_bounds__(256) void hist_kernel(const int* __restrict__ ei, int E, int* __restrict__ count) {
    int e = blockIdx.x * blockDim.x + threadIdx.x;
    if (e < E) atomicAdd(&count[ei[E + e]], 1);   // col = target
}

__global__ __launch_bounds__(256) void dinv_kernel(const int* __restrict__ count, float* __restrict__ dinv, int n) {
    int i = blockIdx.x * blockDim.x + threadIdx.x;
    if (i < n) dinv[i] = rsqrtf((float)(count[i] + 1));   // +1 self-loop
}

// pass 1: per-block (1024 elems) local exclusive scan into rowptr, block total into bsum
__global__ __launch_bounds__(256) void scan_pass1(const int* __restrict__ count, int* __restrict__ rowptr,
                                                  int* __restrict__ bsum, int n) {
    __shared__ int ssum[256];
    int t = threadIdx.x;
    int base = blockIdx.x * SCAN_CHUNK + t * 4;
    int v0 = 0, v1 = 0, v2 = 0, v3 = 0;
    if (base + 3 < n) {
        int4 vv = *(const int4*)(count + base);
        v0 = vv.x; v1 = vv.y; v2 = vv.z; v3 = vv.w;
    } else {
        if (base + 0 < n) v0 = count[base + 0];
        if (base + 1 < n) v1 = count[base + 1];
        if (base + 2 < n) v2 = count[base + 2];
        if (base + 3 < n) v3 = count[base + 3];
    }
    int s = v0 + v1 + v2 + v3;
    ssum[t] = s;
    __syncthreads();
    for (int off = 1; off < 256; off <<= 1) {
        int u = (t >= off) ? ssum[t - off] : 0;
        __syncthreads();
        ssum[t] += u;
        __syncthreads();
    }
    int excl = ssum[t] - s;
    int p0 = excl, p1 = excl + v0, p2 = excl + v0 + v1, p3 = excl + v0 + v1 + v2;
    if (base + 3 < n) {
        *(int4*)(rowptr + base) = make_int4(p0, p1, p2, p3);
    } else {
        if (base + 0 < n) rowptr[base + 0] = p0;
        if (base + 1 < n) rowptr[base + 1] = p1;
        if (base + 2 < n) rowptr[base + 2] = p2;
        if (base + 3 < n) rowptr[base + 3] = p3;
    }
    if (t == 255) bsum[blockIdx.x] = ssum[255];
}

// pass 2: scan block sums (nb <= 1024), write exclusive block offsets + rowptr[n]
__global__ __launch_bounds__(1024) void scan_pass2(const int* __restrict__ bsum, int* __restrict__ boffs,
                                                   int* __restrict__ rowptr, int nb, int n) {
    __shared__ int s[1024];
    int t = threadIdx.x;
    int v = (t < nb) ? bsum[t] : 0;
    s[t] = v;
    __syncthreads();
    for (int off = 1; off < 1024; off <<= 1) {
        int u = (t >= off) ? s[t - off] : 0;
        __syncthreads();
        s[t] += u;
        __syncthreads();
    }
    if (t < nb) boffs[t] = s[t] - v;
    if (t == 1023) rowptr[n] = s[1023];
}

// pass 3: add block offsets, materialize cursor
__global__ __launch_bounds__(256) void scan_pass3(int* __restrict__ rowptr, int* __restrict__ cursor,
                                                  const int* __restrict__ boffs, int n) {
    int t = threadIdx.x;
    int base = blockIdx.x * SCAN_CHUNK + t * 4;
    int off = boffs[blockIdx.x];
    if (base + 3 < n) {
        int4 v = *(int4*)(rowptr + base);
        v.x += off; v.y += off; v.z += off; v.w += off;
        *(int4*)(rowptr + base) = v;
        *(int4*)(cursor + base) = v;
    } else {
        for (int j = 0; j < 4; ++j)
            if (base + j < n) { int v = rowptr[base + j] + off; rowptr[base + j] = v; cursor[base + j] = v; }
    }
}

// scatter: CSR entry = (source index, norm weight dinv[src]*dinv[dst]) packed as int2
__global__ __launch_bounds__(256) void scatter_kernel(const int* __restrict__ ei, int E,
                                                      const float* __restrict__ dinv,
                                                      int* __restrict__ cursor, int2* __restrict__ csrw) {
    int e = blockIdx.x * blockDim.x + threadIdx.x;
    if (e < E) {
        int r = ei[e];          // source
        int c = ei[E + e];      // target
        int pos = atomicAdd(&cursor[c], 1);
        float w = dinv[r] * dinv[c];
        csrw[pos] = make_int2(r, __float_as_int(w));
    }
}

// ---------------- dense GEMM via MFMA: [n,K](f32) @ [K,64](f32) -> [n,64](f16) ----------------
// 64 rows/block, 4 waves; wave w computes rows [w*16,w*16+16) x all 64 cols as
// 4 n-tiles of v_mfma_f32_16x16x32_f16 (fp32 accum). A and W^T staged to LDS as
// fp16, rows padded +8 halves (keeps 16B align for ds_read_b128, breaks the
// 256B-stride bank pattern). Frag layout (verified m89/m120): A[m=lane&15]
// [k=quad*8+j]; B-frag = W^T[n=lane&15][k=quad*8+j]; D: row=quad*4+reg, col=lane&15.

template <int K>
__global__ __launch_bounds__(256) void gemm_kernel(const float* __restrict__ A, const float* __restrict__ W,
                                                   __half* __restrict__ out, int n) {
    const int KP = K + 8;
    __shared__ _Float16 Ah[64 * (K + 8)];
    __shared__ _Float16 Wt[64 * (K + 8)];
    int tid = threadIdx.x;

    // W [K][64] f32 -> Wt[c][k] f16 (coalesced global read)
    for (int idx = tid; idx < K * 64; idx += 256) {
        int k = idx >> 6, c = idx & 63;
        Wt[c * KP + k] = (_Float16)W[idx];
    }
    // A rows -> Ah f16
    int row0 = blockIdx.x * 64;
    const float* Ab = A + (size_t)row0 * K;
    int limit = (n - row0) * K; if (limit > 64 * K) limit = 64 * K;
    for (int f = tid * 4; f < 64 * K; f += 1024) {
        float4 v = make_float4(0.f, 0.f, 0.f, 0.f);
        if (f + 3 < limit) {
            v = *(const float4*)(Ab + f);
        } else {
            if (f + 0 < limit) v.x = Ab[f + 0];
            if (f + 1 < limit) v.y = Ab[f + 1];
            if (f + 2 < limit) v.z = Ab[f + 2];
        }
        int row = f / K, k = f % K;
        _Float16* dst = Ah + row * KP + k;
        dst[0] = (_Float16)v.x; dst[1] = (_Float16)v.y;
        dst[2] = (_Float16)v.z; dst[3] = (_Float16)v.w;
    }
    __syncthreads();

    int w = tid >> 6, lane = tid & 63;
    int m = lane & 15, quad = lane >> 4;
    const _Float16* Aw = Ah + (size_t)(w * 16 + m) * KP + quad * 8;
    const _Float16* Bw = Wt + (size_t)m * KP + quad * 8;

    floatx4 acc0 = {0.f, 0.f, 0.f, 0.f}, acc1 = acc0, acc2 = acc0, acc3 = acc0;
    for (int k0 = 0; k0 < K; k0 += 32) {
        half8 a  = *(const half8*)(Aw + k0);
        half8 b0 = *(const half8*)(Bw + 0 * 16 * KP + k0);
        half8 b1 = *(const half8*)(Bw + 1 * 16 * KP + k0);
        half8 b2 = *(const half8*)(Bw + 2 * 16 * KP + k0);
        half8 b3 = *(const half8*)(Bw + 3 * 16 * KP + k0);
        acc0 = __builtin_amdgcn_mfma_f32_16x16x32_f16(a, b0, acc0, 0, 0, 0);
        acc1 = __builtin_amdgcn_mfma_f32_16x16x32_f16(a, b1, acc1, 0, 0, 0);
        acc2 = __builtin_amdgcn_mfma_f32_16x16x32_f16(a, b2, acc2, 0, 0, 0);
        acc3 = __builtin_amdgcn_mfma_f32_16x16x32_f16(a, b3, acc3, 0, 0, 0);
    }

    int rbase = row0 + w * 16 + quad * 4;
#pragma unroll
    for (int r = 0; r < 4; ++r) {
        int row = rbase + r;
        if (row < n) {
            __half* o = out + (size_t)row * 64 + m;
            o[0]  = __float2half(acc0[r]);
            o[16] = __float2half(acc1[r]);
            o[32] = __float2half(acc2[r]);
            o[48] = __float2half(acc3[r]);
        }
    }
}

// ---------------- aggregation + bias + BN(eval) + ReLU (+classifier) ----------------
// Wave = 2 groups x 32 lanes; lane owns a half2 feature pair; each gather
// instruction fetches 2 different rows (one per group) -> 2x cache lines in
// flight per instruction slot. Unroll 4 -> 8 rows outstanding per wave.

template <bool FUSE_CLS>
__global__ __launch_bounds__(256) void agg_kernel(const __half* __restrict__ t, const float* __restrict__ dinv,
                                                  const int* __restrict__ rowptr, const int2* __restrict__ csrw,
                                                  const float* __restrict__ bias, const float* __restrict__ gamma,
                                                  const float* __restrict__ beta, const float* __restrict__ mean,
                                                  const float* __restrict__ var, float* __restrict__ out,
                                                  const float* __restrict__ cls_w, const float* __restrict__ cls_b,
                                                  int n) {
    int wave = threadIdx.x >> 6;
    int lane = threadIdx.x & 63;
    int g = lane >> 5;          // edge group 0/1
    int fl = lane & 31;         // feature-pair index (features 2*fl, 2*fl+1)
    int i = blockIdx.x * (blockDim.x >> 6) + wave;
    if (i >= n) return;

    const half2* t2 = (const half2*)t;
    float2 acc = make_float2(0.f, 0.f);

    if (g == 0) {   // self-loop counted once
        float di = dinv[i];
        float2 v = __half22float2(t2[(size_t)i * 32 + fl]);
        acc.x = di * di * v.x;
        acc.y = di * di * v.y;
    }

    int e0 = rowptr[i], e1 = rowptr[i + 1];
    int e = e0;
    for (; e + 8 <= e1; e += 8) {
        int2 a0 = csrw[e + 0 + g];
        int2 a1 = csrw[e + 2 + g];
        int2 a2 = csrw[e + 4 + g];
        int2 a3 = csrw[e + 6 + g];
        float2 v0 = __half22float2(t2[(size_t)a0.x * 32 + fl]);
        float2 v1 = __half22float2(t2[(size_t)a1.x * 32 + fl]);
        float2 v2 = __half22float2(t2[(size_t)a2.x * 32 + fl]);
        float2 v3 = __half22float2(t2[(size_t)a3.x * 32 + fl]);
        float w0 = __int_as_float(a0.y), w1 = __int_as_float(a1.y);
        float w2 = __int_as_float(a2.y), w3 = __int_as_float(a3.y);
        acc.x += w0 * v0.x + w1 * v1.x + w2 * v2.x + w3 * v3.x;
        acc.y += w0 * v0.y + w1 * v1.y + w2 * v2.y + w3 * v3.y;
    }
    for (; e + 2 <= e1; e += 2) {
        int2 a = csrw[e + g];
        float2 v = __half22float2(t2[(size_t)a.x * 32 + fl]);
        float w = __int_as_float(a.y);
        acc.x += w * v.x;
        acc.y += w * v.y;
    }
    if (e < e1 && g == 0) {     // odd last edge
        int2 a = csrw[e];
        float2 v = __half22float2(t2[(size_t)a.x * 32 + fl]);
        float w = __int_as_float(a.y);
        acc.x += w * v.x;
        acc.y += w * v.y;
    }

    // combine the two groups
    acc.x += __shfl_xor(acc.x, 32);
    acc.y += __shfl_xor(acc.y, 32);

    // bias + BN(eval) + ReLU on the feature pair
    float2 bb = ((const float2*)bias)[fl];
    float2 gg = ((const float2*)gamma)[fl];
    float2 be = ((const float2*)beta)[fl];
    float2 mm = ((const float2*)mean)[fl];
    float2 vv = ((const float2*)var)[fl];
    float sx = gg.x * rsqrtf(vv.x + EPS);
    float sy = gg.y * rsqrtf(vv.y + EPS);
    float rx = fmaxf((acc.x + bb.x - mm.x) * sx + be.x, 0.f);
    float ry = fmaxf((acc.y + bb.y - mm.y) * sy + be.y, 0.f);

    if (!FUSE_CLS) {
        if (g == 0) ((float2*)out)[(size_t)i * 32 + fl] = make_float2(rx, ry);
    } else {
        // cls_w layout [64][2]; float4 at fl covers features 2fl,2fl+1
        float4 cw = ((const float4*)cls_w)[fl];
        float c0 = rx * cw.x + ry * cw.z;
        float c1 = rx * cw.y + ry * cw.w;
        for (int off = 16; off > 0; off >>= 1) {
            c0 += __shfl_xor(c0, off);
            c1 += __shfl_xor(c1, off);
        }
        if (lane == 0) {
            out[(size_t)i * 2 + 0] = c0 + cls_b[0];
            out[(size_t)i * 2 + 1] = c1 + cls_b[1];
        }
    }
}

// ---------------- launch ----------------

extern "C" void kernel_launch(void* const* d_in, const int* in_sizes, int n_in,
                              void* d_out, int out_size, void* d_ws, size_t ws_size,
                              hipStream_t stream) {
    const float* x      = (const float*)d_in[0];
    const int*   ei     = (const int*)d_in[1];
    const float* w0     = (const float*)d_in[2];
    const float* w1     = (const float*)d_in[3];
    const float* w2     = (const float*)d_in[4];
    const float* biases = (const float*)d_in[5];
    const float* gamma  = (const float*)d_in[6];
    const float* beta   = (const float*)d_in[7];
    const float* rmean  = (const float*)d_in[8];
    const float* rvar   = (const float*)d_in[9];
    const float* cls_w  = (const float*)d_in[10];
    const float* cls_b  = (const float*)d_in[11];
    float* out = (float*)d_out;

    const int IN = 128, H = 64;
    const int N = in_sizes[0] / IN;   // 100000
    const int E = in_sizes[1] / 2;    // 1200000

    char* p = (char*)d_ws;
    auto carve = [&](size_t bytes) { void* q = (void*)p; p += (bytes + 255) & ~(size_t)255; return q; };
    float* dinv   = (float*)carve((size_t)N * 4);
    int*   count  = (int*)carve((size_t)N * 4);
    int*   rowptr = (int*)carve((size_t)(N + 1) * 4);
    int*   cursor = (int*)carve((size_t)N * 4);
    int2*  csrw   = (int2*)carve((size_t)E * 8);
    int*   bsum   = (int*)carve((size_t)1024 * 4);
    int*   boffs  = (int*)carve((size_t)1024 * 4);
    __half* tbuf  = (__half*)carve((size_t)N * H * 2);
    float* hbuf   = (float*)carve((size_t)N * H * 4);

    int nb = (N + SCAN_CHUNK - 1) / SCAN_CHUNK;   // 98 for N=100000

    hipMemsetAsync(count, 0, (size_t)N * 4, stream);
    hist_kernel<<<(E + 255) / 256, 256, 0, stream>>>(ei, E, count);
    dinv_kernel<<<(N + 255) / 256, 256, 0, stream>>>(count, dinv, N);
    scan_pass1<<<nb, 256, 0, stream>>>(count, rowptr, bsum, N);
    scan_pass2<<<1, 1024, 0, stream>>>(bsum, boffs, rowptr, nb, N);
    scan_pass3<<<nb, 256, 0, stream>>>(rowptr, cursor, boffs, N);
    scatter_kernel<<<(E + 255) / 256, 256, 0, stream>>>(ei, E, dinv, cursor, csrw);

    int gemm_grid = (N + 63) / 64;
    int agg_grid  = (N + 3) / 4;

    // layer 0
    gemm_kernel<128><<<gemm_grid, 256, 0, stream>>>(x, w0, tbuf, N);
    agg_kernel<false><<<agg_grid, 256, 0, stream>>>(tbuf, dinv, rowptr, csrw,
        biases + 0, gamma + 0, beta + 0, rmean + 0, rvar + 0, hbuf, nullptr, nullptr, N);
    // layer 1
    gemm_kernel<64><<<gemm_grid, 256, 0, stream>>>(hbuf, w1, tbuf, N);
    agg_kernel<false><<<agg_grid, 256, 0, stream>>>(tbuf, dinv, rowptr, csrw,
        biases + H, gamma + H, beta + H, rmean + H, rvar + H, hbuf, nullptr, nullptr, N);
    // layer 2 + classifier
    gemm_kernel<64><<<gemm_grid, 256, 0, stream>>>(hbuf, w2, tbuf, N);
    agg_kernel<true><<<agg_grid, 256, 0, stream>>>(tbuf, dinv, rowptr, csrw,
        biases + 2 * H, gamma + 2 * H, beta + 2 * H, rmean + 2 * H, rvar + 2 * H, out, cls_w, cls_b, N);
}

// Round 8
// 409.470 us; speedup vs baseline: 7.2677x; 1.0850x over previous
//
#include <hip/hip_runtime.h>
#include <hip/hip_fp16.h>

#define EPS 1e-5f
#define SCAN_CHUNK 1024   // elements per block in the parallel scan
#define ABITS 9           // 512 nodes per target-bucket
#define ACHUNK 4096       // edges per block in bucket pass A

typedef _Float16 half8 __attribute__((ext_vector_type(8)));
typedef float floatx4 __attribute__((ext_vector_type(4)));

// ---------------- graph prep ----------------

__global__ __launch_bounds__(256) void hist_kernel(const int* __restrict__ ei, int E, int* __restrict__ count) {
    int e = blockIdx.x * blockDim.x + threadIdx.x;
    if (e < E) atomicAdd(&count[ei[E + e]], 1);   // col = target
}

__global__ __launch_bounds__(256) void dinv_kernel(const int* __restrict__ count, float* __restrict__ dinv, int n) {
    int i = blockIdx.x * blockDim.x + threadIdx.x;
    if (i < n) dinv[i] = rsqrtf((float)(count[i] + 1));   // +1 self-loop
}

// pass 1: per-block (1024 elems) local exclusive scan into rowptr, block total into bsum
__global__ __launch_bounds__(256) void scan_pass1(const int* __restrict__ count, int* __restrict__ rowptr,
                                                  int* __restrict__ bsum, int n) {
    __shared__ int ssum[256];
    int t = threadIdx.x;
    int base = blockIdx.x * SCAN_CHUNK + t * 4;
    int v0 = 0, v1 = 0, v2 = 0, v3 = 0;
    if (base + 3 < n) {
        int4 vv = *(const int4*)(count + base);
        v0 = vv.x; v1 = vv.y; v2 = vv.z; v3 = vv.w;
    } else {
        if (base + 0 < n) v0 = count[base + 0];
        if (base + 1 < n) v1 = count[base + 1];
        if (base + 2 < n) v2 = count[base + 2];
        if (base + 3 < n) v3 = count[base + 3];
    }
    int s = v0 + v1 + v2 + v3;
    ssum[t] = s;
    __syncthreads();
    for (int off = 1; off < 256; off <<= 1) {
        int u = (t >= off) ? ssum[t - off] : 0;
        __syncthreads();
        ssum[t] += u;
        __syncthreads();
    }
    int excl = ssum[t] - s;
    int p0 = excl, p1 = excl + v0, p2 = excl + v0 + v1, p3 = excl + v0 + v1 + v2;
    if (base + 3 < n) {
        *(int4*)(rowptr + base) = make_int4(p0, p1, p2, p3);
    } else {
        if (base + 0 < n) rowptr[base + 0] = p0;
        if (base + 1 < n) rowptr[base + 1] = p1;
        if (base + 2 < n) rowptr[base + 2] = p2;
        if (base + 3 < n) rowptr[base + 3] = p3;
    }
    if (t == 255) bsum[blockIdx.x] = ssum[255];
}

// pass 2: scan block sums (nb <= 1024), write exclusive block offsets + rowptr[n]
__global__ __launch_bounds__(1024) void scan_pass2(const int* __restrict__ bsum, int* __restrict__ boffs,
                                                   int* __restrict__ rowptr, int nb, int n) {
    __shared__ int s[1024];
    int t = threadIdx.x;
    int v = (t < nb) ? bsum[t] : 0;
    s[t] = v;
    __syncthreads();
    for (int off = 1; off < 1024; off <<= 1) {
        int u = (t >= off) ? s[t - off] : 0;
        __syncthreads();
        s[t] += u;
        __syncthreads();
    }
    if (t < nb) boffs[t] = s[t] - v;
    if (t == 1023) rowptr[n] = s[1023];
}

// pass 3: add block offsets to rowptr
__global__ __launch_bounds__(256) void scan_pass3(int* __restrict__ rowptr,
                                                  const int* __restrict__ boffs, int n) {
    int t = threadIdx.x;
    int base = blockIdx.x * SCAN_CHUNK + t * 4;
    int off = boffs[blockIdx.x];
    if (base + 3 < n) {
        int4 v = *(int4*)(rowptr + base);
        v.x += off; v.y += off; v.z += off; v.w += off;
        *(int4*)(rowptr + base) = v;
    } else {
        for (int j = 0; j < 4; ++j)
            if (base + j < n) rowptr[base + j] += off;
    }
}

// init per-bucket cursors: gcursor[b] = rowptr[b<<ABITS]
__global__ __launch_bounds__(256) void gcinit_kernel(const int* __restrict__ rowptr, int* __restrict__ gcursor,
                                                     int nbuckets, int n) {
    int b = threadIdx.x;
    if (b < nbuckets) {
        int node = b << ABITS; if (node > n) node = n;
        gcursor[b] = rowptr[node];
    }
}

// bucket pass A: scatter (src,tgt) into per-target-bucket regions of tmp.
// Per block: LDS-histogram its 4096-edge chunk over 256 buckets, reserve a
// contiguous run per bucket with ONE global atomic, write grouped -> runs of
// ~20 edges share cache lines (write amp ~1.4x vs 8x for the naive scatter).
__global__ __launch_bounds__(256) void bucketA_kernel(const int* __restrict__ ei, int E,
                                                      int* __restrict__ gcursor, int2* __restrict__ tmp) {
    __shared__ int hist[256], lbase[256], lcur[256];
    int t = threadIdx.x;
    hist[t] = 0; lcur[t] = 0;
    __syncthreads();
    int e0 = blockIdx.x * ACHUNK;
    int e1 = e0 + ACHUNK; if (e1 > E) e1 = E;
    for (int e = e0 + t; e < e1; e += 256)
        atomicAdd(&hist[ei[E + e] >> ABITS], 1);
    __syncthreads();
    int h = hist[t];
    if (h) lbase[t] = atomicAdd(&gcursor[t], h);
    __syncthreads();
    for (int e = e0 + t; e < e1; e += 256) {
        int r = ei[e], c = ei[E + e];
        int b = c >> ABITS;
        int l = atomicAdd(&lcur[b], 1);
        tmp[lbase[b] + l] = make_int2(r, c);
    }
}

// bucket pass B: one block per bucket. Stage rowptr/dinv slices in LDS, then
// place each edge at rowptr[tgt]+lcur[tgt] via LDS cursors. All writes land in
// the bucket's contiguous ~50KB csrw window -> L2 write-combined.
__global__ __launch_bounds__(256) void bucketB_kernel(const int2* __restrict__ tmp, const int* __restrict__ rowptr,
                                                      const float* __restrict__ dinv, int2* __restrict__ csrw,
                                                      int n) {
    __shared__ int lrp[513];
    __shared__ float ldv[512];
    __shared__ int lcur[512];
    int b = blockIdx.x, t = threadIdx.x;
    int n0 = b << ABITS;
    int cnt = n - n0; if (cnt > 512) cnt = 512;
    for (int i = t; i < cnt; i += 256) {
        lrp[i] = rowptr[n0 + i];
        ldv[i] = dinv[n0 + i];
        lcur[i] = 0;
    }
    if (t == 0) lrp[cnt] = rowptr[n0 + cnt];
    __syncthreads();
    int start = lrp[0], end = lrp[cnt];
    for (int idx = start + t; idx < end; idx += 256) {
        int2 st = tmp[idx];
        int lt = st.y - n0;
        int l = atomicAdd(&lcur[lt], 1);
        float w = dinv[st.x] * ldv[lt];
        csrw[lrp[lt] + l] = make_int2(st.x, __float_as_int(w));
    }
}

// ---------------- dense GEMM via MFMA: [n,K](f32) @ [K,64](f32) -> [n,64](f16) ----------------

template <int K>
__global__ __launch_bounds__(256) void gemm_kernel(const float* __restrict__ A, const float* __restrict__ W,
                                                   __half* __restrict__ out, int n) {
    const int KP = K + 8;
    __shared__ _Float16 Ah[64 * (K + 8)];
    __shared__ _Float16 Wt[64 * (K + 8)];
    int tid = threadIdx.x;

    for (int idx = tid; idx < K * 64; idx += 256) {
        int k = idx >> 6, c = idx & 63;
        Wt[c * KP + k] = (_Float16)W[idx];
    }
    int row0 = blockIdx.x * 64;
    const float* Ab = A + (size_t)row0 * K;
    int limit = (n - row0) * K; if (limit > 64 * K) limit = 64 * K;
    for (int f = tid * 4; f < 64 * K; f += 1024) {
        float4 v = make_float4(0.f, 0.f, 0.f, 0.f);
        if (f + 3 < limit) {
            v = *(const float4*)(Ab + f);
        } else {
            if (f + 0 < limit) v.x = Ab[f + 0];
            if (f + 1 < limit) v.y = Ab[f + 1];
            if (f + 2 < limit) v.z = Ab[f + 2];
        }
        int row = f / K, k = f % K;
        _Float16* dst = Ah + row * KP + k;
        dst[0] = (_Float16)v.x; dst[1] = (_Float16)v.y;
        dst[2] = (_Float16)v.z; dst[3] = (_Float16)v.w;
    }
    __syncthreads();

    int w = tid >> 6, lane = tid & 63;
    int m = lane & 15, quad = lane >> 4;
    const _Float16* Aw = Ah + (size_t)(w * 16 + m) * KP + quad * 8;
    const _Float16* Bw = Wt + (size_t)m * KP + quad * 8;

    floatx4 acc0 = {0.f, 0.f, 0.f, 0.f}, acc1 = acc0, acc2 = acc0, acc3 = acc0;
    for (int k0 = 0; k0 < K; k0 += 32) {
        half8 a  = *(const half8*)(Aw + k0);
        half8 b0 = *(const half8*)(Bw + 0 * 16 * KP + k0);
        half8 b1 = *(const half8*)(Bw + 1 * 16 * KP + k0);
        half8 b2 = *(const half8*)(Bw + 2 * 16 * KP + k0);
        half8 b3 = *(const half8*)(Bw + 3 * 16 * KP + k0);
        acc0 = __builtin_amdgcn_mfma_f32_16x16x32_f16(a, b0, acc0, 0, 0, 0);
        acc1 = __builtin_amdgcn_mfma_f32_16x16x32_f16(a, b1, acc1, 0, 0, 0);
        acc2 = __builtin_amdgcn_mfma_f32_16x16x32_f16(a, b2, acc2, 0, 0, 0);
        acc3 = __builtin_amdgcn_mfma_f32_16x16x32_f16(a, b3, acc3, 0, 0, 0);
    }

    int rbase = row0 + w * 16 + quad * 4;
#pragma unroll
    for (int r = 0; r < 4; ++r) {
        int row = rbase + r;
        if (row < n) {
            __half* o = out + (size_t)row * 64 + m;
            o[0]  = __float2half(acc0[r]);
            o[16] = __float2half(acc1[r]);
            o[32] = __float2half(acc2[r]);
            o[48] = __float2half(acc3[r]);
        }
    }
}

// ---------------- aggregation + bias + BN(eval) + ReLU (+classifier) ----------------

template <bool FUSE_CLS>
__global__ __launch_bounds__(256) void agg_kernel(const __half* __restrict__ t, const float* __restrict__ dinv,
                                                  const int* __restrict__ rowptr, const int2* __restrict__ csrw,
                                                  const float* __restrict__ bias, const float* __restrict__ gamma,
                                                  const float* __restrict__ beta, const float* __restrict__ mean,
                                                  const float* __restrict__ var, float* __restrict__ out,
                                                  const float* __restrict__ cls_w, const float* __restrict__ cls_b,
                                                  int n) {
    int wave = threadIdx.x >> 6;
    int lane = threadIdx.x & 63;
    int g = lane >> 5;          // edge group 0/1
    int fl = lane & 31;         // feature-pair index (features 2*fl, 2*fl+1)
    int i = blockIdx.x * (blockDim.x >> 6) + wave;
    if (i >= n) return;

    const half2* t2 = (const half2*)t;
    float2 acc = make_float2(0.f, 0.f);

    if (g == 0) {   // self-loop counted once
        float di = dinv[i];
        float2 v = __half22float2(t2[(size_t)i * 32 + fl]);
        acc.x = di * di * v.x;
        acc.y = di * di * v.y;
    }

    int e0 = rowptr[i], e1 = rowptr[i + 1];
    int e = e0;
    for (; e + 8 <= e1; e += 8) {
        int2 a0 = csrw[e + 0 + g];
        int2 a1 = csrw[e + 2 + g];
        int2 a2 = csrw[e + 4 + g];
        int2 a3 = csrw[e + 6 + g];
        float2 v0 = __half22float2(t2[(size_t)a0.x * 32 + fl]);
        float2 v1 = __half22float2(t2[(size_t)a1.x * 32 + fl]);
        float2 v2 = __half22float2(t2[(size_t)a2.x * 32 + fl]);
        float2 v3 = __half22float2(t2[(size_t)a3.x * 32 + fl]);
        float w0 = __int_as_float(a0.y), w1 = __int_as_float(a1.y);
        float w2 = __int_as_float(a2.y), w3 = __int_as_float(a3.y);
        acc.x += w0 * v0.x + w1 * v1.x + w2 * v2.x + w3 * v3.x;
        acc.y += w0 * v0.y + w1 * v1.y + w2 * v2.y + w3 * v3.y;
    }
    for (; e + 2 <= e1; e += 2) {
        int2 a = csrw[e + g];
        float2 v = __half22float2(t2[(size_t)a.x * 32 + fl]);
        float w = __int_as_float(a.y);
        acc.x += w * v.x;
        acc.y += w * v.y;
    }
    if (e < e1 && g == 0) {     // odd last edge
        int2 a = csrw[e];
        float2 v = __half22float2(t2[(size_t)a.x * 32 + fl]);
        float w = __int_as_float(a.y);
        acc.x += w * v.x;
        acc.y += w * v.y;
    }

    // combine the two groups
    acc.x += __shfl_xor(acc.x, 32);
    acc.y += __shfl_xor(acc.y, 32);

    // bias + BN(eval) + ReLU on the feature pair
    float2 bb = ((const float2*)bias)[fl];
    float2 gg = ((const float2*)gamma)[fl];
    float2 be = ((const float2*)beta)[fl];
    float2 mm = ((const float2*)mean)[fl];
    float2 vv = ((const float2*)var)[fl];
    float sx = gg.x * rsqrtf(vv.x + EPS);
    float sy = gg.y * rsqrtf(vv.y + EPS);
    float rx = fmaxf((acc.x + bb.x - mm.x) * sx + be.x, 0.f);
    float ry = fmaxf((acc.y + bb.y - mm.y) * sy + be.y, 0.f);

    if (!FUSE_CLS) {
        if (g == 0) ((float2*)out)[(size_t)i * 32 + fl] = make_float2(rx, ry);
    } else {
        float4 cw = ((const float4*)cls_w)[fl];
        float c0 = rx * cw.x + ry * cw.z;
        float c1 = rx * cw.y + ry * cw.w;
        for (int off = 16; off > 0; off >>= 1) {
            c0 += __shfl_xor(c0, off);
            c1 += __shfl_xor(c1, off);
        }
        if (lane == 0) {
            out[(size_t)i * 2 + 0] = c0 + cls_b[0];
            out[(size_t)i * 2 + 1] = c1 + cls_b[1];
        }
    }
}

// ---------------- launch ----------------

extern "C" void kernel_launch(void* const* d_in, const int* in_sizes, int n_in,
                              void* d_out, int out_size, void* d_ws, size_t ws_size,
                              hipStream_t stream) {
    const float* x      = (const float*)d_in[0];
    const int*   ei     = (const int*)d_in[1];
    const float* w0     = (const float*)d_in[2];
    const float* w1     = (const float*)d_in[3];
    const float* w2     = (const float*)d_in[4];
    const float* biases = (const float*)d_in[5];
    const float* gamma  = (const float*)d_in[6];
    const float* beta   = (const float*)d_in[7];
    const float* rmean  = (const float*)d_in[8];
    const float* rvar   = (const float*)d_in[9];
    const float* cls_w  = (const float*)d_in[10];
    const float* cls_b  = (const float*)d_in[11];
    float* out = (float*)d_out;

    const int IN = 128, H = 64;
    const int N = in_sizes[0] / IN;   // 100000
    const int E = in_sizes[1] / 2;    // 1200000

    char* p = (char*)d_ws;
    auto carve = [&](size_t bytes) { void* q = (void*)p; p += (bytes + 255) & ~(size_t)255; return q; };
    float* dinv   = (float*)carve((size_t)N * 4);
    int*   count  = (int*)carve((size_t)N * 4);
    int*   rowptr = (int*)carve((size_t)(N + 1) * 4);
    int2*  tmp    = (int2*)carve((size_t)E * 8);
    int2*  csrw   = (int2*)carve((size_t)E * 8);
    int*   gcursor= (int*)carve((size_t)256 * 4);
    int*   bsum   = (int*)carve((size_t)1024 * 4);
    int*   boffs  = (int*)carve((size_t)1024 * 4);
    __half* tbuf  = (__half*)carve((size_t)N * H * 2);
    float* hbuf   = (float*)carve((size_t)N * H * 4);

    int nb = (N + SCAN_CHUNK - 1) / SCAN_CHUNK;       // 98 for N=100000
    int nbuckets = (N + (1 << ABITS) - 1) >> ABITS;   // 196 for N=100000

    hipMemsetAsync(count, 0, (size_t)N * 4, stream);
    hist_kernel<<<(E + 255) / 256, 256, 0, stream>>>(ei, E, count);
    dinv_kernel<<<(N + 255) / 256, 256, 0, stream>>>(count, dinv, N);
    scan_pass1<<<nb, 256, 0, stream>>>(count, rowptr, bsum, N);
    scan_pass2<<<1, 1024, 0, stream>>>(bsum, boffs, rowptr, nb, N);
    scan_pass3<<<nb, 256, 0, stream>>>(rowptr, boffs, N);
    gcinit_kernel<<<1, 256, 0, stream>>>(rowptr, gcursor, nbuckets, N);
    bucketA_kernel<<<(E + ACHUNK - 1) / ACHUNK, 256, 0, stream>>>(ei, E, gcursor, tmp);
    bucketB_kernel<<<nbuckets, 256, 0, stream>>>(tmp, rowptr, dinv, csrw, N);

    int gemm_grid = (N + 63) / 64;
    int agg_grid  = (N + 3) / 4;

    // layer 0
    gemm_kernel<128><<<gemm_grid, 256, 0, stream>>>(x, w0, tbuf, N);
    agg_kernel<false><<<agg_grid, 256, 0, stream>>>(tbuf, dinv, rowptr, csrw,
        biases + 0, gamma + 0, beta + 0, rmean + 0, rvar + 0, hbuf, nullptr, nullptr, N);
    // layer 1
    gemm_kernel<64><<<gemm_grid, 256, 0, stream>>>(hbuf, w1, tbuf, N);
    agg_kernel<false><<<agg_grid, 256, 0, stream>>>(tbuf, dinv, rowptr, csrw,
        biases + H, gamma + H, beta + H, rmean + H, rvar + H, hbuf, nullptr, nullptr, N);
    // layer 2 + classifier
    gemm_kernel<64><<<gemm_grid, 256, 0, stream>>>(hbuf, w2, tbuf, N);
    agg_kernel<true><<<agg_grid, 256, 0, stream>>>(tbuf, dinv, rowptr, csrw,
        biases + 2 * H, gamma + 2 * H, beta + 2 * H, rmean + 2 * H, rvar + 2 * H, out, cls_w, cls_b, N);
}

// Round 9
// 389.145 us; speedup vs baseline: 7.6473x; 1.0522x over previous
//
#include <hip/hip_runtime.h>
#include <hip/hip_fp16.h>

#define EPS 1e-5f
#define SCAN_CHUNK 1024   // elements per block in the parallel scan
#define ABITS 9           // 512 nodes per target-bucket
#define ACHUNK 4096       // edges per block in bucket pass A

typedef _Float16 half8 __attribute__((ext_vector_type(8)));
typedef float floatx4 __attribute__((ext_vector_type(4)));

// ---------------- graph prep ----------------

__global__ __launch_bounds__(256) void hist_kernel(const int* __restrict__ ei, int E, int* __restrict__ count) {
    int e = blockIdx.x * blockDim.x + threadIdx.x;
    if (e < E) atomicAdd(&count[ei[E + e]], 1);   // col = target
}

__global__ __launch_bounds__(256) void dinv_kernel(const int* __restrict__ count, float* __restrict__ dinv, int n) {
    int i = blockIdx.x * blockDim.x + threadIdx.x;
    if (i < n) dinv[i] = rsqrtf((float)(count[i] + 1));   // +1 self-loop
}

// pass 1: per-block (1024 elems) local exclusive scan into rowptr, block total into bsum
__global__ __launch_bounds__(256) void scan_pass1(const int* __restrict__ count, int* __restrict__ rowptr,
                                                  int* __restrict__ bsum, int n) {
    __shared__ int ssum[256];
    int t = threadIdx.x;
    int base = blockIdx.x * SCAN_CHUNK + t * 4;
    int v0 = 0, v1 = 0, v2 = 0, v3 = 0;
    if (base + 3 < n) {
        int4 vv = *(const int4*)(count + base);
        v0 = vv.x; v1 = vv.y; v2 = vv.z; v3 = vv.w;
    } else {
        if (base + 0 < n) v0 = count[base + 0];
        if (base + 1 < n) v1 = count[base + 1];
        if (base + 2 < n) v2 = count[base + 2];
        if (base + 3 < n) v3 = count[base + 3];
    }
    int s = v0 + v1 + v2 + v3;
    ssum[t] = s;
    __syncthreads();
    for (int off = 1; off < 256; off <<= 1) {
        int u = (t >= off) ? ssum[t - off] : 0;
        __syncthreads();
        ssum[t] += u;
        __syncthreads();
    }
    int excl = ssum[t] - s;
    int p0 = excl, p1 = excl + v0, p2 = excl + v0 + v1, p3 = excl + v0 + v1 + v2;
    if (base + 3 < n) {
        *(int4*)(rowptr + base) = make_int4(p0, p1, p2, p3);
    } else {
        if (base + 0 < n) rowptr[base + 0] = p0;
        if (base + 1 < n) rowptr[base + 1] = p1;
        if (base + 2 < n) rowptr[base + 2] = p2;
        if (base + 3 < n) rowptr[base + 3] = p3;
    }
    if (t == 255) bsum[blockIdx.x] = ssum[255];
}

// pass 2: scan block sums (nb <= 1024), write exclusive block offsets + rowptr[n]
__global__ __launch_bounds__(1024) void scan_pass2(const int* __restrict__ bsum, int* __restrict__ boffs,
                                                   int* __restrict__ rowptr, int nb, int n) {
    __shared__ int s[1024];
    int t = threadIdx.x;
    int v = (t < nb) ? bsum[t] : 0;
    s[t] = v;
    __syncthreads();
    for (int off = 1; off < 1024; off <<= 1) {
        int u = (t >= off) ? s[t - off] : 0;
        __syncthreads();
        s[t] += u;
        __syncthreads();
    }
    if (t < nb) boffs[t] = s[t] - v;
    if (t == 1023) rowptr[n] = s[1023];
}

// pass 3: add block offsets to rowptr
__global__ __launch_bounds__(256) void scan_pass3(int* __restrict__ rowptr,
                                                  const int* __restrict__ boffs, int n) {
    int t = threadIdx.x;
    int base = blockIdx.x * SCAN_CHUNK + t * 4;
    int off = boffs[blockIdx.x];
    if (base + 3 < n) {
        int4 v = *(int4*)(rowptr + base);
        v.x += off; v.y += off; v.z += off; v.w += off;
        *(int4*)(rowptr + base) = v;
    } else {
        for (int j = 0; j < 4; ++j)
            if (base + j < n) rowptr[base + j] += off;
    }
}

// init per-bucket cursors: gcursor[b] = rowptr[b<<ABITS]
__global__ __launch_bounds__(256) void gcinit_kernel(const int* __restrict__ rowptr, int* __restrict__ gcursor,
                                                     int nbuckets, int n) {
    int b = threadIdx.x;
    if (b < nbuckets) {
        int node = b << ABITS; if (node > n) node = n;
        gcursor[b] = rowptr[node];
    }
}

// bucket pass A: scatter (src,tgt) into per-target-bucket regions of tmp.
__global__ __launch_bounds__(256) void bucketA_kernel(const int* __restrict__ ei, int E,
                                                      int* __restrict__ gcursor, int2* __restrict__ tmp) {
    __shared__ int hist[256], lbase[256], lcur[256];
    int t = threadIdx.x;
    hist[t] = 0; lcur[t] = 0;
    __syncthreads();
    int e0 = blockIdx.x * ACHUNK;
    int e1 = e0 + ACHUNK; if (e1 > E) e1 = E;
    for (int e = e0 + t; e < e1; e += 256)
        atomicAdd(&hist[ei[E + e] >> ABITS], 1);
    __syncthreads();
    int h = hist[t];
    if (h) lbase[t] = atomicAdd(&gcursor[t], h);
    __syncthreads();
    for (int e = e0 + t; e < e1; e += 256) {
        int r = ei[e], c = ei[E + e];
        int b = c >> ABITS;
        int l = atomicAdd(&lcur[b], 1);
        tmp[lbase[b] + l] = make_int2(r, c);
    }
}

// bucket pass B: one block per bucket; exact placement via LDS cursors.
__global__ __launch_bounds__(256) void bucketB_kernel(const int2* __restrict__ tmp, const int* __restrict__ rowptr,
                                                      const float* __restrict__ dinv, int2* __restrict__ csrw,
                                                      int n) {
    __shared__ int lrp[513];
    __shared__ float ldv[512];
    __shared__ int lcur[512];
    int b = blockIdx.x, t = threadIdx.x;
    int n0 = b << ABITS;
    int cnt = n - n0; if (cnt > 512) cnt = 512;
    for (int i = t; i < cnt; i += 256) {
        lrp[i] = rowptr[n0 + i];
        ldv[i] = dinv[n0 + i];
        lcur[i] = 0;
    }
    if (t == 0) lrp[cnt] = rowptr[n0 + cnt];
    __syncthreads();
    int start = lrp[0], end = lrp[cnt];
    for (int idx = start + t; idx < end; idx += 256) {
        int2 st = tmp[idx];
        int lt = st.y - n0;
        int l = atomicAdd(&lcur[lt], 1);
        float w = dinv[st.x] * ldv[lt];
        csrw[lrp[lt] + l] = make_int2(st.x, __float_as_int(w));
    }
}

// ---------------- dense GEMM via MFMA: [n,K](f32) @ [K,64](f32) -> [n,64](f16) ----------------

template <int K>
__global__ __launch_bounds__(256) void gemm_kernel(const float* __restrict__ A, const float* __restrict__ W,
                                                   __half* __restrict__ out, int n) {
    const int KP = K + 8;
    __shared__ _Float16 Ah[64 * (K + 8)];
    __shared__ _Float16 Wt[64 * (K + 8)];
    int tid = threadIdx.x;

    for (int idx = tid; idx < K * 64; idx += 256) {
        int k = idx >> 6, c = idx & 63;
        Wt[c * KP + k] = (_Float16)W[idx];
    }
    int row0 = blockIdx.x * 64;
    const float* Ab = A + (size_t)row0 * K;
    int limit = (n - row0) * K; if (limit > 64 * K) limit = 64 * K;
    for (int f = tid * 4; f < 64 * K; f += 1024) {
        float4 v = make_float4(0.f, 0.f, 0.f, 0.f);
        if (f + 3 < limit) {
            v = *(const float4*)(Ab + f);
        } else {
            if (f + 0 < limit) v.x = Ab[f + 0];
            if (f + 1 < limit) v.y = Ab[f + 1];
            if (f + 2 < limit) v.z = Ab[f + 2];
        }
        int row = f / K, k = f % K;
        _Float16* dst = Ah + row * KP + k;
        dst[0] = (_Float16)v.x; dst[1] = (_Float16)v.y;
        dst[2] = (_Float16)v.z; dst[3] = (_Float16)v.w;
    }
    __syncthreads();

    int w = tid >> 6, lane = tid & 63;
    int m = lane & 15, quad = lane >> 4;
    const _Float16* Aw = Ah + (size_t)(w * 16 + m) * KP + quad * 8;
    const _Float16* Bw = Wt + (size_t)m * KP + quad * 8;

    floatx4 acc0 = {0.f, 0.f, 0.f, 0.f}, acc1 = acc0, acc2 = acc0, acc3 = acc0;
    for (int k0 = 0; k0 < K; k0 += 32) {
        half8 a  = *(const half8*)(Aw + k0);
        half8 b0 = *(const half8*)(Bw + 0 * 16 * KP + k0);
        half8 b1 = *(const half8*)(Bw + 1 * 16 * KP + k0);
        half8 b2 = *(const half8*)(Bw + 2 * 16 * KP + k0);
        half8 b3 = *(const half8*)(Bw + 3 * 16 * KP + k0);
        acc0 = __builtin_amdgcn_mfma_f32_16x16x32_f16(a, b0, acc0, 0, 0, 0);
        acc1 = __builtin_amdgcn_mfma_f32_16x16x32_f16(a, b1, acc1, 0, 0, 0);
        acc2 = __builtin_amdgcn_mfma_f32_16x16x32_f16(a, b2, acc2, 0, 0, 0);
        acc3 = __builtin_amdgcn_mfma_f32_16x16x32_f16(a, b3, acc3, 0, 0, 0);
    }

    int rbase = row0 + w * 16 + quad * 4;
#pragma unroll
    for (int r = 0; r < 4; ++r) {
        int row = rbase + r;
        if (row < n) {
            __half* o = out + (size_t)row * 64 + m;
            o[0]  = __float2half(acc0[r]);
            o[16] = __float2half(acc1[r]);
            o[32] = __float2half(acc2[r]);
            o[48] = __float2half(acc3[r]);
        }
    }
}

// ---------------- aggregation + bias + BN(eval) + ReLU (+classifier) ----------------
// Wave = 4 groups x 16 lanes; lane owns a feature QUAD (8 B); 16 lanes cover the
// 128 B row. Each wave-instruction gathers 4 edges (one per group) -> 2x fewer
// VALU slots per edge than the 2x32 scheme, and up to 16 loads in flight
// (stride-16 tier), 8 (stride-8), 4 (stride-4), predicated tail.

#define AGG_ACC(aw, raw)  { float _w = __int_as_float((aw).y);                         \
    float2 _lo = __half22float2(*(const __half2*)&(raw).x);                            \
    float2 _hi = __half22float2(*(const __half2*)&(raw).y);                            \
    acc.x += _w * _lo.x; acc.y += _w * _lo.y; acc.z += _w * _hi.x; acc.w += _w * _hi.y; }

template <bool FUSE_CLS>
__global__ __launch_bounds__(256) void agg_kernel(const __half* __restrict__ t, const float* __restrict__ dinv,
                                                  const int* __restrict__ rowptr, const int2* __restrict__ csrw,
                                                  const float* __restrict__ bias, const float* __restrict__ gamma,
                                                  const float* __restrict__ beta, const float* __restrict__ mean,
                                                  const float* __restrict__ var, float* __restrict__ out,
                                                  const float* __restrict__ cls_w, const float* __restrict__ cls_b,
                                                  int n) {
    int wave = threadIdx.x >> 6;
    int lane = threadIdx.x & 63;
    int g = lane >> 4;          // edge group 0..3
    int fl = lane & 15;         // feature quad: features 4fl..4fl+3
    int i = blockIdx.x * (blockDim.x >> 6) + wave;
    if (i >= n) return;

    float4 acc = make_float4(0.f, 0.f, 0.f, 0.f);

    if (g == 0) {   // self-loop counted once
        float di = dinv[i];
        uint2 raw = *(const uint2*)(t + (size_t)i * 64 + fl * 4);
        int2 self = make_int2(0, __float_as_int(di * di));
        AGG_ACC(self, raw);
    }

    int e0 = rowptr[i], e1 = rowptr[i + 1];
    int e = e0;
    for (; e + 16 <= e1; e += 16) {          // 16 gathers in flight per wave
        int base = e + g * 4;
        int2 a0 = csrw[base + 0], a1 = csrw[base + 1], a2 = csrw[base + 2], a3 = csrw[base + 3];
        uint2 r0 = *(const uint2*)(t + (size_t)a0.x * 64 + fl * 4);
        uint2 r1 = *(const uint2*)(t + (size_t)a1.x * 64 + fl * 4);
        uint2 r2 = *(const uint2*)(t + (size_t)a2.x * 64 + fl * 4);
        uint2 r3 = *(const uint2*)(t + (size_t)a3.x * 64 + fl * 4);
        AGG_ACC(a0, r0); AGG_ACC(a1, r1); AGG_ACC(a2, r2); AGG_ACC(a3, r3);
    }
    for (; e + 8 <= e1; e += 8) {            // 8 in flight
        int2 a0 = csrw[e + g * 2 + 0], a1 = csrw[e + g * 2 + 1];
        uint2 r0 = *(const uint2*)(t + (size_t)a0.x * 64 + fl * 4);
        uint2 r1 = *(const uint2*)(t + (size_t)a1.x * 64 + fl * 4);
        AGG_ACC(a0, r0); AGG_ACC(a1, r1);
    }
    for (; e + 4 <= e1; e += 4) {            // 4 in flight
        int2 a = csrw[e + g];
        uint2 r = *(const uint2*)(t + (size_t)a.x * 64 + fl * 4);
        AGG_ACC(a, r);
    }
    if (g < e1 - e) {                        // tail 0..3 edges, predicated
        int2 a = csrw[e + g];
        uint2 r = *(const uint2*)(t + (size_t)a.x * 64 + fl * 4);
        AGG_ACC(a, r);
    }

    // combine the four groups
    acc.x += __shfl_xor(acc.x, 16); acc.y += __shfl_xor(acc.y, 16);
    acc.z += __shfl_xor(acc.z, 16); acc.w += __shfl_xor(acc.w, 16);
    acc.x += __shfl_xor(acc.x, 32); acc.y += __shfl_xor(acc.y, 32);
    acc.z += __shfl_xor(acc.z, 32); acc.w += __shfl_xor(acc.w, 32);

    // bias + BN(eval) + ReLU on the feature quad
    float4 bb = ((const float4*)bias)[fl];
    float4 gg = ((const float4*)gamma)[fl];
    float4 be = ((const float4*)beta)[fl];
    float4 mm = ((const float4*)mean)[fl];
    float4 vv = ((const float4*)var)[fl];
    float4 res;
    res.x = fmaxf((acc.x + bb.x - mm.x) * (gg.x * rsqrtf(vv.x + EPS)) + be.x, 0.f);
    res.y = fmaxf((acc.y + bb.y - mm.y) * (gg.y * rsqrtf(vv.y + EPS)) + be.y, 0.f);
    res.z = fmaxf((acc.z + bb.z - mm.z) * (gg.z * rsqrtf(vv.z + EPS)) + be.z, 0.f);
    res.w = fmaxf((acc.w + bb.w - mm.w) * (gg.w * rsqrtf(vv.w + EPS)) + be.w, 0.f);

    if (!FUSE_CLS) {
        if (lane < 16) ((float4*)out)[(size_t)i * 16 + fl] = res;
    } else {
        // cls_w layout [64][2]; rows 4fl..4fl+3 -> two float4s
        float4 cwA = ((const float4*)cls_w)[2 * fl + 0];   // rows 4fl, 4fl+1
        float4 cwB = ((const float4*)cls_w)[2 * fl + 1];   // rows 4fl+2, 4fl+3
        float c0 = res.x * cwA.x + res.y * cwA.z + res.z * cwB.x + res.w * cwB.z;
        float c1 = res.x * cwA.y + res.y * cwA.w + res.z * cwB.y + res.w * cwB.w;
        for (int off = 8; off > 0; off >>= 1) {
            c0 += __shfl_xor(c0, off);
            c1 += __shfl_xor(c1, off);
        }
        if (lane == 0) {
            out[(size_t)i * 2 + 0] = c0 + cls_b[0];
            out[(size_t)i * 2 + 1] = c1 + cls_b[1];
        }
    }
}

// ---------------- launch ----------------

extern "C" void kernel_launch(void* const* d_in, const int* in_sizes, int n_in,
                              void* d_out, int out_size, void* d_ws, size_t ws_size,
                              hipStream_t stream) {
    const float* x      = (const float*)d_in[0];
    const int*   ei     = (const int*)d_in[1];
    const float* w0     = (const float*)d_in[2];
    const float* w1     = (const float*)d_in[3];
    const float* w2     = (const float*)d_in[4];
    const float* biases = (const float*)d_in[5];
    const float* gamma  = (const float*)d_in[6];
    const float* beta   = (const float*)d_in[7];
    const float* rmean  = (const float*)d_in[8];
    const float* rvar   = (const float*)d_in[9];
    const float* cls_w  = (const float*)d_in[10];
    const float* cls_b  = (const float*)d_in[11];
    float* out = (float*)d_out;

    const int IN = 128, H = 64;
    const int N = in_sizes[0] / IN;   // 100000
    const int E = in_sizes[1] / 2;    // 1200000

    char* p = (char*)d_ws;
    auto carve = [&](size_t bytes) { void* q = (void*)p; p += (bytes + 255) & ~(size_t)255; return q; };
    float* dinv   = (float*)carve((size_t)N * 4);
    int*   count  = (int*)carve((size_t)N * 4);
    int*   rowptr = (int*)carve((size_t)(N + 1) * 4);
    int2*  tmp    = (int2*)carve((size_t)E * 8);
    int2*  csrw   = (int2*)carve((size_t)E * 8);
    int*   gcursor= (int*)carve((size_t)256 * 4);
    int*   bsum   = (int*)carve((size_t)1024 * 4);
    int*   boffs  = (int*)carve((size_t)1024 * 4);
    __half* tbuf  = (__half*)carve((size_t)N * H * 2);
    float* hbuf   = (float*)carve((size_t)N * H * 4);

    int nb = (N + SCAN_CHUNK - 1) / SCAN_CHUNK;       // 98 for N=100000
    int nbuckets = (N + (1 << ABITS) - 1) >> ABITS;   // 196 for N=100000

    hipMemsetAsync(count, 0, (size_t)N * 4, stream);
    hist_kernel<<<(E + 255) / 256, 256, 0, stream>>>(ei, E, count);
    dinv_kernel<<<(N + 255) / 256, 256, 0, stream>>>(count, dinv, N);
    scan_pass1<<<nb, 256, 0, stream>>>(count, rowptr, bsum, N);
    scan_pass2<<<1, 1024, 0, stream>>>(bsum, boffs, rowptr, nb, N);
    scan_pass3<<<nb, 256, 0, stream>>>(rowptr, boffs, N);
    gcinit_kernel<<<1, 256, 0, stream>>>(rowptr, gcursor, nbuckets, N);
    bucketA_kernel<<<(E + ACHUNK - 1) / ACHUNK, 256, 0, stream>>>(ei, E, gcursor, tmp);
    bucketB_kernel<<<nbuckets, 256, 0, stream>>>(tmp, rowptr, dinv, csrw, N);

    int gemm_grid = (N + 63) / 64;
    int agg_grid  = (N + 3) / 4;

    // layer 0
    gemm_kernel<128><<<gemm_grid, 256, 0, stream>>>(x, w0, tbuf, N);
    agg_kernel<false><<<agg_grid, 256, 0, stream>>>(tbuf, dinv, rowptr, csrw,
        biases + 0, gamma + 0, beta + 0, rmean + 0, rvar + 0, hbuf, nullptr, nullptr, N);
    // layer 1
    gemm_kernel<64><<<gemm_grid, 256, 0, stream>>>(hbuf, w1, tbuf, N);
    agg_kernel<false><<<agg_grid, 256, 0, stream>>>(tbuf, dinv, rowptr, csrw,
        biases + H, gamma + H, beta + H, rmean + H, rvar + H, hbuf, nullptr, nullptr, N);
    // layer 2 + classifier
    gemm_kernel<64><<<gemm_grid, 256, 0, stream>>>(hbuf, w2, tbuf, N);
    agg_kernel<true><<<agg_grid, 256, 0, stream>>>(tbuf, dinv, rowptr, csrw,
        biases + 2 * H, gamma + 2 * H, beta + 2 * H, rmean + 2 * H, rvar + 2 * H, out, cls_w, cls_b, N);
}

// Round 11
// 333.513 us; speedup vs baseline: 8.9229x; 1.1668x over previous
//
#include <hip/hip_runtime.h>
#include <hip/hip_fp16.h>

#define EPS 1e-5f
#define SCAN_CHUNK 1024   // elements per block in the parallel scan
#define ABITS 9           // 512 nodes per target-bucket
#define ACHUNK 4096       // edges per block in bucket pass A

typedef _Float16 half8 __attribute__((ext_vector_type(8)));
typedef float floatx4 __attribute__((ext_vector_type(4)));

// ---------------- graph prep ----------------

__global__ __launch_bounds__(256) void hist_kernel(const int* __restrict__ ei, int E, int* __restrict__ count) {
    int e = blockIdx.x * blockDim.x + threadIdx.x;
    if (e < E) atomicAdd(&count[ei[E + e]], 1);   // col = target
}

__global__ __launch_bounds__(256) void dinv_kernel(const int* __restrict__ count, float* __restrict__ dinv, int n) {
    int i = blockIdx.x * blockDim.x + threadIdx.x;
    if (i < n) dinv[i] = rsqrtf((float)(count[i] + 1));   // +1 self-loop
}

// pass 1: per-block (1024 elems) local exclusive scan into rowptr, block total into bsum
__global__ __launch_bounds__(256) void scan_pass1(const int* __restrict__ count, int* __restrict__ rowptr,
                                                  int* __restrict__ bsum, int n) {
    __shared__ int ssum[256];
    int t = threadIdx.x;
    int base = blockIdx.x * SCAN_CHUNK + t * 4;
    int v0 = 0, v1 = 0, v2 = 0, v3 = 0;
    if (base + 3 < n) {
        int4 vv = *(const int4*)(count + base);
        v0 = vv.x; v1 = vv.y; v2 = vv.z; v3 = vv.w;
    } else {
        if (base + 0 < n) v0 = count[base + 0];
        if (base + 1 < n) v1 = count[base + 1];
        if (base + 2 < n) v2 = count[base + 2];
        if (base + 3 < n) v3 = count[base + 3];
    }
    int s = v0 + v1 + v2 + v3;
    ssum[t] = s;
    __syncthreads();
    for (int off = 1; off < 256; off <<= 1) {
        int u = (t >= off) ? ssum[t - off] : 0;
        __syncthreads();
        ssum[t] += u;
        __syncthreads();
    }
    int excl = ssum[t] - s;
    int p0 = excl, p1 = excl + v0, p2 = excl + v0 + v1, p3 = excl + v0 + v1 + v2;
    if (base + 3 < n) {
        *(int4*)(rowptr + base) = make_int4(p0, p1, p2, p3);
    } else {
        if (base + 0 < n) rowptr[base + 0] = p0;
        if (base + 1 < n) rowptr[base + 1] = p1;
        if (base + 2 < n) rowptr[base + 2] = p2;
        if (base + 3 < n) rowptr[base + 3] = p3;
    }
    if (t == 255) bsum[blockIdx.x] = ssum[255];
}

// pass 2: scan block sums (nb <= 1024), write exclusive block offsets + rowptr[n]
__global__ __launch_bounds__(1024) void scan_pass2(const int* __restrict__ bsum, int* __restrict__ boffs,
                                                   int* __restrict__ rowptr, int nb, int n) {
    __shared__ int s[1024];
    int t = threadIdx.x;
    int v = (t < nb) ? bsum[t] : 0;
    s[t] = v;
    __syncthreads();
    for (int off = 1; off < 1024; off <<= 1) {
        int u = (t >= off) ? s[t - off] : 0;
        __syncthreads();
        s[t] += u;
        __syncthreads();
    }
    if (t < nb) boffs[t] = s[t] - v;
    if (t == 1023) rowptr[n] = s[1023];
}

// pass 3: add block offsets to rowptr
__global__ __launch_bounds__(256) void scan_pass3(int* __restrict__ rowptr,
                                                  const int* __restrict__ boffs, int n) {
    int t = threadIdx.x;
    int base = blockIdx.x * SCAN_CHUNK + t * 4;
    int off = boffs[blockIdx.x];
    if (base + 3 < n) {
        int4 v = *(int4*)(rowptr + base);
        v.x += off; v.y += off; v.z += off; v.w += off;
        *(int4*)(rowptr + base) = v;
    } else {
        for (int j = 0; j < 4; ++j)
            if (base + j < n) rowptr[base + j] += off;
    }
}

// init per-bucket cursors: gcursor[b] = rowptr[b<<ABITS]
__global__ __launch_bounds__(256) void gcinit_kernel(const int* __restrict__ rowptr, int* __restrict__ gcursor,
                                                     int nbuckets, int n) {
    int b = threadIdx.x;
    if (b < nbuckets) {
        int node = b << ABITS; if (node > n) node = n;
        gcursor[b] = rowptr[node];
    }
}

// bucket pass A: scatter (src,tgt) into per-target-bucket regions of tmp.
__global__ __launch_bounds__(256) void bucketA_kernel(const int* __restrict__ ei, int E,
                                                      int* __restrict__ gcursor, int2* __restrict__ tmp) {
    __shared__ int hist[256], lbase[256], lcur[256];
    int t = threadIdx.x;
    hist[t] = 0; lcur[t] = 0;
    __syncthreads();
    int e0 = blockIdx.x * ACHUNK;
    int e1 = e0 + ACHUNK; if (e1 > E) e1 = E;
    for (int e = e0 + t; e < e1; e += 256)
        atomicAdd(&hist[ei[E + e] >> ABITS], 1);
    __syncthreads();
    int h = hist[t];
    if (h) lbase[t] = atomicAdd(&gcursor[t], h);
    __syncthreads();
    for (int e = e0 + t; e < e1; e += 256) {
        int r = ei[e], c = ei[E + e];
        int b = c >> ABITS;
        int l = atomicAdd(&lcur[b], 1);
        tmp[lbase[b] + l] = make_int2(r, c);
    }
}

// bucket pass B: one block per bucket; exact placement via LDS cursors.
__global__ __launch_bounds__(256) void bucketB_kernel(const int2* __restrict__ tmp, const int* __restrict__ rowptr,
                                                      const float* __restrict__ dinv, int2* __restrict__ csrw,
                                                      int n) {
    __shared__ int lrp[513];
    __shared__ float ldv[512];
    __shared__ int lcur[512];
    int b = blockIdx.x, t = threadIdx.x;
    int n0 = b << ABITS;
    int cnt = n - n0; if (cnt > 512) cnt = 512;
    for (int i = t; i < cnt; i += 256) {
        lrp[i] = rowptr[n0 + i];
        ldv[i] = dinv[n0 + i];
        lcur[i] = 0;
    }
    if (t == 0) lrp[cnt] = rowptr[n0 + cnt];
    __syncthreads();
    int start = lrp[0], end = lrp[cnt];
    for (int idx = start + t; idx < end; idx += 256) {
        int2 st = tmp[idx];
        int lt = st.y - n0;
        int l = atomicAdd(&lcur[lt], 1);
        float w = dinv[st.x] * ldv[lt];
        csrw[lrp[lt] + l] = make_int2(st.x, __float_as_int(w));
    }
}

// ---------------- dense GEMM via MFMA: [n,K](f32) @ [K,64](f32) -> [n,64](f16) ----------------

template <int K>
__global__ __launch_bounds__(256) void gemm_kernel(const float* __restrict__ A, const float* __restrict__ W,
                                                   __half* __restrict__ out, int n) {
    const int KP = K + 8;
    __shared__ _Float16 Ah[64 * (K + 8)];
    __shared__ _Float16 Wt[64 * (K + 8)];
    int tid = threadIdx.x;

    for (int idx = tid; idx < K * 64; idx += 256) {
        int k = idx >> 6, c = idx & 63;
        Wt[c * KP + k] = (_Float16)W[idx];
    }
    int row0 = blockIdx.x * 64;
    const float* Ab = A + (size_t)row0 * K;
    int limit = (n - row0) * K; if (limit > 64 * K) limit = 64 * K;
    for (int f = tid * 4; f < 64 * K; f += 1024) {
        float4 v = make_float4(0.f, 0.f, 0.f, 0.f);
        if (f + 3 < limit) {
            v = *(const float4*)(Ab + f);
        } else {
            if (f + 0 < limit) v.x = Ab[f + 0];
            if (f + 1 < limit) v.y = Ab[f + 1];
            if (f + 2 < limit) v.z = Ab[f + 2];
        }
        int row = f / K, k = f % K;
        _Float16* dst = Ah + row * KP + k;
        dst[0] = (_Float16)v.x; dst[1] = (_Float16)v.y;
        dst[2] = (_Float16)v.z; dst[3] = (_Float16)v.w;
    }
    __syncthreads();

    int w = tid >> 6, lane = tid & 63;
    int m = lane & 15, quad = lane >> 4;
    const _Float16* Aw = Ah + (size_t)(w * 16 + m) * KP + quad * 8;
    const _Float16* Bw = Wt + (size_t)m * KP + quad * 8;

    floatx4 acc0 = {0.f, 0.f, 0.f, 0.f}, acc1 = acc0, acc2 = acc0, acc3 = acc0;
    for (int k0 = 0; k0 < K; k0 += 32) {
        half8 a  = *(const half8*)(Aw + k0);
        half8 b0 = *(const half8*)(Bw + 0 * 16 * KP + k0);
        half8 b1 = *(const half8*)(Bw + 1 * 16 * KP + k0);
        half8 b2 = *(const half8*)(Bw + 2 * 16 * KP + k0);
        half8 b3 = *(const half8*)(Bw + 3 * 16 * KP + k0);
        acc0 = __builtin_amdgcn_mfma_f32_16x16x32_f16(a, b0, acc0, 0, 0, 0);
        acc1 = __builtin_amdgcn_mfma_f32_16x16x32_f16(a, b1, acc1, 0, 0, 0);
        acc2 = __builtin_amdgcn_mfma_f32_16x16x32_f16(a, b2, acc2, 0, 0, 0);
        acc3 = __builtin_amdgcn_mfma_f32_16x16x32_f16(a, b3, acc3, 0, 0, 0);
    }

    int rbase = row0 + w * 16 + quad * 4;
#pragma unroll
    for (int r = 0; r < 4; ++r) {
        int row = rbase + r;
        if (row < n) {
            __half* o = out + (size_t)row * 64 + m;
            o[0]  = __float2half(acc0[r]);
            o[16] = __float2half(acc1[r]);
            o[32] = __float2half(acc2[r]);
            o[48] = __float2half(acc3[r]);
        }
    }
}

// ---------------- aggregation + bias + BN(eval) + ReLU (+classifier) ----------------
// Wave = 4 independent 16-lane groups, ONE NODE PER GROUP. Lane owns a feature
// quad (8 B); 16 lanes cover the 128 B row. Each group runs its own unroll-4
// edge loop -> 4 loads in flight per group x 4 groups = 16 gathers in flight
// per wave at EVERY degree (R9's tiered scheme only reached 16 at deg>=16).

__device__ __forceinline__ void agg_accw(float4& acc, float wgt, uint2 raw) {
    float2 lo = __half22float2(*(const __half2*)&raw.x);
    float2 hi = __half22float2(*(const __half2*)&raw.y);
    acc.x += wgt * lo.x; acc.y += wgt * lo.y;
    acc.z += wgt * hi.x; acc.w += wgt * hi.y;
}

template <bool FUSE_CLS>
__global__ __launch_bounds__(256) void agg_kernel(const __half* __restrict__ t, const float* __restrict__ dinv,
                                                  const int* __restrict__ rowptr, const int2* __restrict__ csrw,
                                                  const float* __restrict__ bias, const float* __restrict__ gamma,
                                                  const float* __restrict__ beta, const float* __restrict__ mean,
                                                  const float* __restrict__ var, float* __restrict__ out,
                                                  const float* __restrict__ cls_w, const float* __restrict__ cls_b,
                                                  int n) {
    int wave = threadIdx.x >> 6;
    int lane = threadIdx.x & 63;
    int g = lane >> 4;          // group 0..3 = node slot
    int fl = lane & 15;         // feature quad: features 4fl..4fl+3
    int i = (blockIdx.x * (blockDim.x >> 6) + wave) * 4 + g;
    if (i >= n) return;

    float4 acc = make_float4(0.f, 0.f, 0.f, 0.f);

    // self-loop
    float di = dinv[i];
    uint2 self = *(const uint2*)(t + (size_t)i * 64 + fl * 4);
    agg_accw(acc, di * di, self);

    int e0 = rowptr[i], e1 = rowptr[i + 1];
    int e = e0;
    for (; e + 4 <= e1; e += 4) {            // 4 in flight per group, 16/wave
        int2 a0 = csrw[e + 0], a1 = csrw[e + 1], a2 = csrw[e + 2], a3 = csrw[e + 3];
        uint2 r0 = *(const uint2*)(t + (size_t)a0.x * 64 + fl * 4);
        uint2 r1 = *(const uint2*)(t + (size_t)a1.x * 64 + fl * 4);
        uint2 r2 = *(const uint2*)(t + (size_t)a2.x * 64 + fl * 4);
        uint2 r3 = *(const uint2*)(t + (size_t)a3.x * 64 + fl * 4);
        agg_accw(acc, __int_as_float(a0.y), r0);
        agg_accw(acc, __int_as_float(a1.y), r1);
        agg_accw(acc, __int_as_float(a2.y), r2);
        agg_accw(acc, __int_as_float(a3.y), r3);
    }
    if (e + 2 <= e1) {                        // 2-tail
        int2 a0 = csrw[e + 0], a1 = csrw[e + 1];
        uint2 r0 = *(const uint2*)(t + (size_t)a0.x * 64 + fl * 4);
        uint2 r1 = *(const uint2*)(t + (size_t)a1.x * 64 + fl * 4);
        agg_accw(acc, __int_as_float(a0.y), r0);
        agg_accw(acc, __int_as_float(a1.y), r1);
        e += 2;
    }
    if (e < e1) {                             // 1-tail
        int2 a = csrw[e];
        uint2 r = *(const uint2*)(t + (size_t)a.x * 64 + fl * 4);
        agg_accw(acc, __int_as_float(a.y), r);
    }

    // bias + BN(eval) + ReLU on the feature quad
    float4 bb = ((const float4*)bias)[fl];
    float4 gg = ((const float4*)gamma)[fl];
    float4 be = ((const float4*)beta)[fl];
    float4 mm = ((const float4*)mean)[fl];
    float4 vv = ((const float4*)var)[fl];
    float4 res;
    res.x = fmaxf((acc.x + bb.x - mm.x) * (gg.x * rsqrtf(vv.x + EPS)) + be.x, 0.f);
    res.y = fmaxf((acc.y + bb.y - mm.y) * (gg.y * rsqrtf(vv.y + EPS)) + be.y, 0.f);
    res.z = fmaxf((acc.z + bb.z - mm.z) * (gg.z * rsqrtf(vv.z + EPS)) + be.z, 0.f);
    res.w = fmaxf((acc.w + bb.w - mm.w) * (gg.w * rsqrtf(vv.w + EPS)) + be.w, 0.f);

    if (!FUSE_CLS) {
        ((float4*)out)[(size_t)i * 16 + fl] = res;
    } else {
        // cls_w layout [64][2]; rows 4fl..4fl+3 -> two float4s
        float4 cwA = ((const float4*)cls_w)[2 * fl + 0];   // rows 4fl, 4fl+1
        float4 cwB = ((const float4*)cls_w)[2 * fl + 1];   // rows 4fl+2, 4fl+3
        float c0 = res.x * cwA.x + res.y * cwA.z + res.z * cwB.x + res.w * cwB.z;
        float c1 = res.x * cwA.y + res.y * cwA.w + res.z * cwB.y + res.w * cwB.w;
        for (int off = 8; off > 0; off >>= 1) {   // reduce within 16-lane group
            c0 += __shfl_xor(c0, off);
            c1 += __shfl_xor(c1, off);
        }
        if (fl == 0) {
            out[(size_t)i * 2 + 0] = c0 + cls_b[0];
            out[(size_t)i * 2 + 1] = c1 + cls_b[1];
        }
    }
}

// ---------------- launch ----------------

extern "C" void kernel_launch(void* const* d_in, const int* in_sizes, int n_in,
                              void* d_out, int out_size, void* d_ws, size_t ws_size,
                              hipStream_t stream) {
    const float* x      = (const float*)d_in[0];
    const int*   ei     = (const int*)d_in[1];
    const float* w0     = (const float*)d_in[2];
    const float* w1     = (const float*)d_in[3];
    const float* w2     = (const float*)d_in[4];
    const float* biases = (const float*)d_in[5];
    const float* gamma  = (const float*)d_in[6];
    const float* beta   = (const float*)d_in[7];
    const float* rmean  = (const float*)d_in[8];
    const float* rvar   = (const float*)d_in[9];
    const float* cls_w  = (const float*)d_in[10];
    const float* cls_b  = (const float*)d_in[11];
    float* out = (float*)d_out;

    const int IN = 128, H = 64;
    const int N = in_sizes[0] / IN;   // 100000
    const int E = in_sizes[1] / 2;    // 1200000

    char* p = (char*)d_ws;
    auto carve = [&](size_t bytes) { void* q = (void*)p; p += (bytes + 255) & ~(size_t)255; return q; };
    float* dinv   = (float*)carve((size_t)N * 4);
    int*   count  = (int*)carve((size_t)N * 4);
    int*   rowptr = (int*)carve((size_t)(N + 1) * 4);
    int2*  tmp    = (int2*)carve((size_t)E * 8);
    int2*  csrw   = (int2*)carve((size_t)E * 8);
    int*   gcursor= (int*)carve((size_t)256 * 4);
    int*   bsum   = (int*)carve((size_t)1024 * 4);
    int*   boffs  = (int*)carve((size_t)1024 * 4);
    __half* tbuf  = (__half*)carve((size_t)N * H * 2);
    float* hbuf   = (float*)carve((size_t)N * H * 4);

    int nb = (N + SCAN_CHUNK - 1) / SCAN_CHUNK;       // 98 for N=100000
    int nbuckets = (N + (1 << ABITS) - 1) >> ABITS;   // 196 for N=100000

    hipMemsetAsync(count, 0, (size_t)N * 4, stream);
    hist_kernel<<<(E + 255) / 256, 256, 0, stream>>>(ei, E, count);
    dinv_kernel<<<(N + 255) / 256, 256, 0, stream>>>(count, dinv, N);
    scan_pass1<<<nb, 256, 0, stream>>>(count, rowptr, bsum, N);
    scan_pass2<<<1, 1024, 0, stream>>>(bsum, boffs, rowptr, nb, N);
    scan_pass3<<<nb, 256, 0, stream>>>(rowptr, boffs, N);
    gcinit_kernel<<<1, 256, 0, stream>>>(rowptr, gcursor, nbuckets, N);
    bucketA_kernel<<<(E + ACHUNK - 1) / ACHUNK, 256, 0, stream>>>(ei, E, gcursor, tmp);
    bucketB_kernel<<<nbuckets, 256, 0, stream>>>(tmp, rowptr, dinv, csrw, N);

    int gemm_grid = (N + 63) / 64;
    int agg_grid  = (N + 15) / 16;   // 16 nodes per block (4 waves x 4 groups)

    // layer 0
    gemm_kernel<128><<<gemm_grid, 256, 0, stream>>>(x, w0, tbuf, N);
    agg_kernel<false><<<agg_grid, 256, 0, stream>>>(tbuf, dinv, rowptr, csrw,
        biases + 0, gamma + 0, beta + 0, rmean + 0, rvar + 0, hbuf, nullptr, nullptr, N);
    // layer 1
    gemm_kernel<64><<<gemm_grid, 256, 0, stream>>>(hbuf, w1, tbuf, N);
    agg_kernel<false><<<agg_grid, 256, 0, stream>>>(tbuf, dinv, rowptr, csrw,
        biases + H, gamma + H, beta + H, rmean + H, rvar + H, hbuf, nullptr, nullptr, N);
    // layer 2 + classifier
    gemm_kernel<64><<<gemm_grid, 256, 0, stream>>>(hbuf, w2, tbuf, N);
    agg_kernel<true><<<agg_grid, 256, 0, stream>>>(tbuf, dinv, rowptr, csrw,
        biases + 2 * H, gamma + 2 * H, beta + 2 * H, rmean + 2 * H, rvar + 2 * H, out, cls_w, cls_b, N);
}

// Round 12
// 283.634 us; speedup vs baseline: 10.4921x; 1.1759x over previous
//
#include <hip/hip_runtime.h>
#include <hip/hip_fp16.h>

#define EPS 1e-5f
#define ABITS 9           // 512 nodes per target-bucket
#define ACHUNK 4096       // edges per block in bucket pass A

typedef _Float16 half8 __attribute__((ext_vector_type(8)));
typedef float floatx4 __attribute__((ext_vector_type(4)));

// ---------------- graph prep: bucketed, no global-atomic histogram ----------------

// A1: per-block LDS histogram over 256 target-buckets, one global atomic per bucket.
__global__ __launch_bounds__(256) void bucketA1_kernel(const int* __restrict__ ei, int E,
                                                       int* __restrict__ bucket_count) {
    __shared__ int hist[256];
    int t = threadIdx.x;
    hist[t] = 0;
    __syncthreads();
    int e0 = blockIdx.x * ACHUNK;
    int e1 = e0 + ACHUNK; if (e1 > E) e1 = E;
    for (int e = e0 + t; e < e1; e += 256)
        atomicAdd(&hist[ei[E + e] >> ABITS], 1);
    __syncthreads();
    int h = hist[t];
    if (h) atomicAdd(&bucket_count[t], h);
}

// bscan: scan 256 bucket counts -> bucket_off[257], init bucket_cursor, rowptr[n]=E.
__global__ __launch_bounds__(256) void bscan_kernel(const int* __restrict__ bucket_count,
                                                    int* __restrict__ bucket_off, int* __restrict__ bucket_cursor,
                                                    int* __restrict__ rowptr, int nbuckets, int n) {
    __shared__ int s[256];
    int t = threadIdx.x;
    int v = bucket_count[t];
    s[t] = v;
    __syncthreads();
    for (int off = 1; off < 256; off <<= 1) {
        int u = (t >= off) ? s[t - off] : 0;
        __syncthreads();
        s[t] += u;
        __syncthreads();
    }
    int excl = s[t] - v;
    if (t < nbuckets) { bucket_off[t] = excl; bucket_cursor[t] = excl; }
    if (t == 255) { bucket_off[nbuckets] = s[255]; rowptr[n] = s[255]; }
}

// A2: scatter (src,tgt) into per-bucket regions of tmp (block-run reservation).
__global__ __launch_bounds__(256) void bucketA2_kernel(const int* __restrict__ ei, int E,
                                                       int* __restrict__ bucket_cursor, int2* __restrict__ tmp) {
    __shared__ int hist[256], lbase[256], lcur[256];
    int t = threadIdx.x;
    hist[t] = 0; lcur[t] = 0;
    __syncthreads();
    int e0 = blockIdx.x * ACHUNK;
    int e1 = e0 + ACHUNK; if (e1 > E) e1 = E;
    for (int e = e0 + t; e < e1; e += 256)
        atomicAdd(&hist[ei[E + e] >> ABITS], 1);
    __syncthreads();
    int h = hist[t];
    if (h) lbase[t] = atomicAdd(&bucket_cursor[t], h);
    __syncthreads();
    for (int e = e0 + t; e < e1; e += 256) {
        int r = ei[e], c = ei[E + e];
        int b = c >> ABITS;
        int l = atomicAdd(&lcur[b], 1);
        tmp[lbase[b] + l] = make_int2(r, c);
    }
}

// B1: per bucket: LDS per-node degree count (LDS atomics only), 512-entry LDS scan,
// write rowptr slice + dinv (rsqrt(count+1), self-loop included).
__global__ __launch_bounds__(256) void bucketB1_kernel(const int2* __restrict__ tmp,
                                                       const int* __restrict__ bucket_off,
                                                       int* __restrict__ rowptr, float* __restrict__ dinv,
                                                       int n) {
    __shared__ int cnt[512];
    __shared__ int ps[256];
    int b = blockIdx.x, t = threadIdx.x;
    int n0 = b << ABITS;
    int cntN = n - n0; if (cntN > 512) cntN = 512;
    cnt[t] = 0; cnt[t + 256] = 0;
    __syncthreads();
    int start = bucket_off[b], end = bucket_off[b + 1];
    for (int idx = start + t; idx < end; idx += 256)
        atomicAdd(&cnt[tmp[idx].y - n0], 1);
    __syncthreads();
    int c0 = cnt[2 * t], c1 = cnt[2 * t + 1];
    int s = c0 + c1;
    ps[t] = s;
    __syncthreads();
    for (int off = 1; off < 256; off <<= 1) {
        int u = (t >= off) ? ps[t - off] : 0;
        __syncthreads();
        ps[t] += u;
        __syncthreads();
    }
    int excl = ps[t] - s;
    int i0 = 2 * t, i1 = 2 * t + 1;
    if (i0 < cntN) {
        rowptr[n0 + i0] = start + excl;
        dinv[n0 + i0] = rsqrtf((float)(c0 + 1));
    }
    if (i1 < cntN) {
        rowptr[n0 + i1] = start + excl + c0;
        dinv[n0 + i1] = rsqrtf((float)(c1 + 1));
    }
}

// B2: per bucket: exact placement of (src, weight) via LDS cursors. dinv complete
// (written by B1, previous kernel) so dinv[src] gathers are safe; 400 KB table is
// L2-resident.
__global__ __launch_bounds__(256) void bucketB2_kernel(const int2* __restrict__ tmp,
                                                       const int* __restrict__ bucket_off,
                                                       const int* __restrict__ rowptr,
                                                       const float* __restrict__ dinv, int2* __restrict__ csrw,
                                                       int n) {
    __shared__ int lrp[512];
    __shared__ float ldv[512];
    __shared__ int lcur[512];
    int b = blockIdx.x, t = threadIdx.x;
    int n0 = b << ABITS;
    int cntN = n - n0; if (cntN > 512) cntN = 512;
    for (int i = t; i < cntN; i += 256) {
        lrp[i] = rowptr[n0 + i];
        ldv[i] = dinv[n0 + i];
        lcur[i] = 0;
    }
    __syncthreads();
    int start = bucket_off[b], end = bucket_off[b + 1];
    for (int idx = start + t; idx < end; idx += 256) {
        int2 st = tmp[idx];
        int lt = st.y - n0;
        int l = atomicAdd(&lcur[lt], 1);
        float w = dinv[st.x] * ldv[lt];
        csrw[lrp[lt] + l] = make_int2(st.x, __float_as_int(w));
    }
}

// ---------------- dense GEMM via MFMA: [n,K](f32) @ [K,64](f32) -> [n,64](f16) ----------------

template <int K>
__global__ __launch_bounds__(256) void gemm_kernel(const float* __restrict__ A, const float* __restrict__ W,
                                                   __half* __restrict__ out, int n) {
    const int KP = K + 8;
    __shared__ _Float16 Ah[64 * (K + 8)];
    __shared__ _Float16 Wt[64 * (K + 8)];
    int tid = threadIdx.x;

    for (int idx = tid; idx < K * 64; idx += 256) {
        int k = idx >> 6, c = idx & 63;
        Wt[c * KP + k] = (_Float16)W[idx];
    }
    int row0 = blockIdx.x * 64;
    const float* Ab = A + (size_t)row0 * K;
    int limit = (n - row0) * K; if (limit > 64 * K) limit = 64 * K;
    for (int f = tid * 4; f < 64 * K; f += 1024) {
        float4 v = make_float4(0.f, 0.f, 0.f, 0.f);
        if (f + 3 < limit) {
            v = *(const float4*)(Ab + f);
        } else {
            if (f + 0 < limit) v.x = Ab[f + 0];
            if (f + 1 < limit) v.y = Ab[f + 1];
            if (f + 2 < limit) v.z = Ab[f + 2];
        }
        int row = f / K, k = f % K;
        _Float16* dst = Ah + row * KP + k;
        dst[0] = (_Float16)v.x; dst[1] = (_Float16)v.y;
        dst[2] = (_Float16)v.z; dst[3] = (_Float16)v.w;
    }
    __syncthreads();

    int w = tid >> 6, lane = tid & 63;
    int m = lane & 15, quad = lane >> 4;
    const _Float16* Aw = Ah + (size_t)(w * 16 + m) * KP + quad * 8;
    const _Float16* Bw = Wt + (size_t)m * KP + quad * 8;

    floatx4 acc0 = {0.f, 0.f, 0.f, 0.f}, acc1 = acc0, acc2 = acc0, acc3 = acc0;
    for (int k0 = 0; k0 < K; k0 += 32) {
        half8 a  = *(const half8*)(Aw + k0);
        half8 b0 = *(const half8*)(Bw + 0 * 16 * KP + k0);
        half8 b1 = *(const half8*)(Bw + 1 * 16 * KP + k0);
        half8 b2 = *(const half8*)(Bw + 2 * 16 * KP + k0);
        half8 b3 = *(const half8*)(Bw + 3 * 16 * KP + k0);
        acc0 = __builtin_amdgcn_mfma_f32_16x16x32_f16(a, b0, acc0, 0, 0, 0);
        acc1 = __builtin_amdgcn_mfma_f32_16x16x32_f16(a, b1, acc1, 0, 0, 0);
        acc2 = __builtin_amdgcn_mfma_f32_16x16x32_f16(a, b2, acc2, 0, 0, 0);
        acc3 = __builtin_amdgcn_mfma_f32_16x16x32_f16(a, b3, acc3, 0, 0, 0);
    }

    int rbase = row0 + w * 16 + quad * 4;
#pragma unroll
    for (int r = 0; r < 4; ++r) {
        int row = rbase + r;
        if (row < n) {
            __half* o = out + (size_t)row * 64 + m;
            o[0]  = __float2half(acc0[r]);
            o[16] = __float2half(acc1[r]);
            o[32] = __float2half(acc2[r]);
            o[48] = __float2half(acc3[r]);
        }
    }
}

// ---------------- aggregation + bias + BN(eval) + ReLU (+classifier) ----------------
// Wave = 8 independent 8-lane groups, ONE NODE PER GROUP. Lane owns a feature
// OCTET (16 B uint4); 8 lanes cover the 128 B row. Unroll-4 edge loop -> up to
// 32 gathers in flight per wave; VALU slots per edge halved vs R11's 4x16.

__device__ __forceinline__ void agg_acc8(float4& lo, float4& hi, float wgt, uint4 raw) {
    float2 p0 = __half22float2(*(const __half2*)&raw.x);
    float2 p1 = __half22float2(*(const __half2*)&raw.y);
    float2 p2 = __half22float2(*(const __half2*)&raw.z);
    float2 p3 = __half22float2(*(const __half2*)&raw.w);
    lo.x += wgt * p0.x; lo.y += wgt * p0.y; lo.z += wgt * p1.x; lo.w += wgt * p1.y;
    hi.x += wgt * p2.x; hi.y += wgt * p2.y; hi.z += wgt * p3.x; hi.w += wgt * p3.y;
}

template <bool FUSE_CLS>
__global__ __launch_bounds__(256) void agg_kernel(const __half* __restrict__ t, const float* __restrict__ dinv,
                                                  const int* __restrict__ rowptr, const int2* __restrict__ csrw,
                                                  const float* __restrict__ bias, const float* __restrict__ gamma,
                                                  const float* __restrict__ beta, const float* __restrict__ mean,
                                                  const float* __restrict__ var, float* __restrict__ out,
                                                  const float* __restrict__ cls_w, const float* __restrict__ cls_b,
                                                  int n) {
    int wave = threadIdx.x >> 6;
    int lane = threadIdx.x & 63;
    int g = lane >> 3;          // group 0..7 = node slot
    int fl = lane & 7;          // feature octet: features 8fl..8fl+7
    int i = (blockIdx.x * (blockDim.x >> 6) + wave) * 8 + g;
    if (i >= n) return;

    float4 lo = make_float4(0.f, 0.f, 0.f, 0.f);
    float4 hi = make_float4(0.f, 0.f, 0.f, 0.f);

    // self-loop
    float di = dinv[i];
    uint4 self = *(const uint4*)(t + (size_t)i * 64 + fl * 8);
    agg_acc8(lo, hi, di * di, self);

    int e0 = rowptr[i], e1 = rowptr[i + 1];
    int e = e0;
    for (; e + 4 <= e1; e += 4) {            // 4 in flight per group, 32/wave
        int2 a0 = csrw[e + 0], a1 = csrw[e + 1], a2 = csrw[e + 2], a3 = csrw[e + 3];
        uint4 r0 = *(const uint4*)(t + (size_t)a0.x * 64 + fl * 8);
        uint4 r1 = *(const uint4*)(t + (size_t)a1.x * 64 + fl * 8);
        uint4 r2 = *(const uint4*)(t + (size_t)a2.x * 64 + fl * 8);
        uint4 r3 = *(const uint4*)(t + (size_t)a3.x * 64 + fl * 8);
        agg_acc8(lo, hi, __int_as_float(a0.y), r0);
        agg_acc8(lo, hi, __int_as_float(a1.y), r1);
        agg_acc8(lo, hi, __int_as_float(a2.y), r2);
        agg_acc8(lo, hi, __int_as_float(a3.y), r3);
    }
    if (e + 2 <= e1) {                        // 2-tail
        int2 a0 = csrw[e + 0], a1 = csrw[e + 1];
        uint4 r0 = *(const uint4*)(t + (size_t)a0.x * 64 + fl * 8);
        uint4 r1 = *(const uint4*)(t + (size_t)a1.x * 64 + fl * 8);
        agg_acc8(lo, hi, __int_as_float(a0.y), r0);
        agg_acc8(lo, hi, __int_as_float(a1.y), r1);
        e += 2;
    }
    if (e < e1) {                             // 1-tail
        int2 a = csrw[e];
        uint4 r = *(const uint4*)(t + (size_t)a.x * 64 + fl * 8);
        agg_acc8(lo, hi, __int_as_float(a.y), r);
    }

    // bias + BN(eval) + ReLU on the feature octet
    float4 bbL = ((const float4*)bias)[2 * fl],  bbH = ((const float4*)bias)[2 * fl + 1];
    float4 ggL = ((const float4*)gamma)[2 * fl], ggH = ((const float4*)gamma)[2 * fl + 1];
    float4 beL = ((const float4*)beta)[2 * fl],  beH = ((const float4*)beta)[2 * fl + 1];
    float4 mmL = ((const float4*)mean)[2 * fl],  mmH = ((const float4*)mean)[2 * fl + 1];
    float4 vvL = ((const float4*)var)[2 * fl],   vvH = ((const float4*)var)[2 * fl + 1];
    float4 resL, resH;
    resL.x = fmaxf((lo.x + bbL.x - mmL.x) * (ggL.x * rsqrtf(vvL.x + EPS)) + beL.x, 0.f);
    resL.y = fmaxf((lo.y + bbL.y - mmL.y) * (ggL.y * rsqrtf(vvL.y + EPS)) + beL.y, 0.f);
    resL.z = fmaxf((lo.z + bbL.z - mmL.z) * (ggL.z * rsqrtf(vvL.z + EPS)) + beL.z, 0.f);
    resL.w = fmaxf((lo.w + bbL.w - mmL.w) * (ggL.w * rsqrtf(vvL.w + EPS)) + beL.w, 0.f);
    resH.x = fmaxf((hi.x + bbH.x - mmH.x) * (ggH.x * rsqrtf(vvH.x + EPS)) + beH.x, 0.f);
    resH.y = fmaxf((hi.y + bbH.y - mmH.y) * (ggH.y * rsqrtf(vvH.y + EPS)) + beH.y, 0.f);
    resH.z = fmaxf((hi.z + bbH.z - mmH.z) * (ggH.z * rsqrtf(vvH.z + EPS)) + beH.z, 0.f);
    resH.w = fmaxf((hi.w + bbH.w - mmH.w) * (ggH.w * rsqrtf(vvH.w + EPS)) + beH.w, 0.f);

    if (!FUSE_CLS) {
        ((float4*)out)[(size_t)i * 16 + 2 * fl + 0] = resL;
        ((float4*)out)[(size_t)i * 16 + 2 * fl + 1] = resH;
    } else {
        // cls_w layout [64][2]; rows 8fl..8fl+7 -> four float4s (2 rows each)
        const float4* cw = (const float4*)cls_w;
        float4 cwA = cw[4 * fl + 0], cwB = cw[4 * fl + 1], cwC = cw[4 * fl + 2], cwD = cw[4 * fl + 3];
        float c0 = resL.x * cwA.x + resL.y * cwA.z + resL.z * cwB.x + resL.w * cwB.z
                 + resH.x * cwC.x + resH.y * cwC.z + resH.z * cwD.x + resH.w * cwD.z;
        float c1 = resL.x * cwA.y + resL.y * cwA.w + resL.z * cwB.y + resL.w * cwB.w
                 + resH.x * cwC.y + resH.y * cwC.w + resH.z * cwD.y + resH.w * cwD.w;
        for (int off = 4; off > 0; off >>= 1) {   // reduce within 8-lane group
            c0 += __shfl_xor(c0, off);
            c1 += __shfl_xor(c1, off);
        }
        if (fl == 0) {
            out[(size_t)i * 2 + 0] = c0 + cls_b[0];
            out[(size_t)i * 2 + 1] = c1 + cls_b[1];
        }
    }
}

// ---------------- launch ----------------

extern "C" void kernel_launch(void* const* d_in, const int* in_sizes, int n_in,
                              void* d_out, int out_size, void* d_ws, size_t ws_size,
                              hipStream_t stream) {
    const float* x      = (const float*)d_in[0];
    const int*   ei     = (const int*)d_in[1];
    const float* w0     = (const float*)d_in[2];
    const float* w1     = (const float*)d_in[3];
    const float* w2     = (const float*)d_in[4];
    const float* biases = (const float*)d_in[5];
    const float* gamma  = (const float*)d_in[6];
    const float* beta   = (const float*)d_in[7];
    const float* rmean  = (const float*)d_in[8];
    const float* rvar   = (const float*)d_in[9];
    const float* cls_w  = (const float*)d_in[10];
    const float* cls_b  = (const float*)d_in[11];
    float* out = (float*)d_out;

    const int IN = 128, H = 64;
    const int N = in_sizes[0] / IN;   // 100000
    const int E = in_sizes[1] / 2;    // 1200000

    char* p = (char*)d_ws;
    auto carve = [&](size_t bytes) { void* q = (void*)p; p += (bytes + 255) & ~(size_t)255; return q; };
    float* dinv    = (float*)carve((size_t)N * 4);
    int*   rowptr  = (int*)carve((size_t)(N + 1) * 4);
    int2*  tmp     = (int2*)carve((size_t)E * 8);
    int2*  csrw    = (int2*)carve((size_t)E * 8);
    int*   bucket_count  = (int*)carve((size_t)256 * 4);
    int*   bucket_off    = (int*)carve((size_t)257 * 4);
    int*   bucket_cursor = (int*)carve((size_t)256 * 4);
    __half* tbuf   = (__half*)carve((size_t)N * H * 2);
    float* hbuf    = (float*)carve((size_t)N * H * 4);

    int nbuckets = (N + (1 << ABITS) - 1) >> ABITS;   // 196 for N=100000
    int na = (E + ACHUNK - 1) / ACHUNK;               // 293

    hipMemsetAsync(bucket_count, 0, (size_t)256 * 4, stream);
    bucketA1_kernel<<<na, 256, 0, stream>>>(ei, E, bucket_count);
    bscan_kernel<<<1, 256, 0, stream>>>(bucket_count, bucket_off, bucket_cursor, rowptr, nbuckets, N);
    bucketA2_kernel<<<na, 256, 0, stream>>>(ei, E, bucket_cursor, tmp);
    bucketB1_kernel<<<nbuckets, 256, 0, stream>>>(tmp, bucket_off, rowptr, dinv, N);
    bucketB2_kernel<<<nbuckets, 256, 0, stream>>>(tmp, bucket_off, rowptr, dinv, csrw, N);

    int gemm_grid = (N + 63) / 64;
    int agg_grid  = (N + 31) / 32;   // 32 nodes per block (4 waves x 8 groups)

    // layer 0
    gemm_kernel<128><<<gemm_grid, 256, 0, stream>>>(x, w0, tbuf, N);
    agg_kernel<false><<<agg_grid, 256, 0, stream>>>(tbuf, dinv, rowptr, csrw,
        biases + 0, gamma + 0, beta + 0, rmean + 0, rvar + 0, hbuf, nullptr, nullptr, N);
    // layer 1
    gemm_kernel<64><<<gemm_grid, 256, 0, stream>>>(hbuf, w1, tbuf, N);
    agg_kernel<false><<<agg_grid, 256, 0, stream>>>(tbuf, dinv, rowptr, csrw,
        biases + H, gamma + H, beta + H, rmean + H, rvar + H, hbuf, nullptr, nullptr, N);
    // layer 2 + classifier
    gemm_kernel<64><<<gemm_grid, 256, 0, stream>>>(hbuf, w2, tbuf, N);
    agg_kernel<true><<<agg_grid, 256, 0, stream>>>(tbuf, dinv, rowptr, csrw,
        biases + 2 * H, gamma + 2 * H, beta + 2 * H, rmean + 2 * H, rvar + 2 * H, out, cls_w, cls_b, N);
}

// Round 13
// 273.850 us; speedup vs baseline: 10.8669x; 1.0357x over previous
//
#include <hip/hip_runtime.h>
#include <hip/hip_fp16.h>

#define EPS 1e-5f
#define ABITS 9           // 512 nodes per target-bucket
#define ACHUNK 4096       // edges per block in bucket pass A
#define BMAX 8192         // max edges staged in LDS per bucket (avg ~6150)

typedef _Float16 half8 __attribute__((ext_vector_type(8)));
typedef float floatx4 __attribute__((ext_vector_type(4)));

// ---------------- graph prep ----------------
// Normalization is factored: gemm scales row r by dinv[r] (source factor), agg
// multiplies by dinv[dst] once per node. So csr stores ONLY the src index.

// A1: per-block LDS histogram over 256 target-buckets, one global atomic per bucket.
__global__ __launch_bounds__(256) void bucketA1_kernel(const int* __restrict__ ei, int E,
                                                       int* __restrict__ bucket_count) {
    __shared__ int hist[256];
    int t = threadIdx.x;
    hist[t] = 0;
    __syncthreads();
    int e0 = blockIdx.x * ACHUNK;
    int e1 = e0 + ACHUNK; if (e1 > E) e1 = E;
    for (int e = e0 + t; e < e1; e += 256)
        atomicAdd(&hist[ei[E + e] >> ABITS], 1);
    __syncthreads();
    int h = hist[t];
    if (h) atomicAdd(&bucket_count[t], h);
}

// bscan: scan 256 bucket counts -> bucket_off[257], init bucket_cursor, rowptr[n]=E.
__global__ __launch_bounds__(256) void bscan_kernel(const int* __restrict__ bucket_count,
                                                    int* __restrict__ bucket_off, int* __restrict__ bucket_cursor,
                                                    int* __restrict__ rowptr, int nbuckets, int n) {
    __shared__ int s[256];
    int t = threadIdx.x;
    int v = bucket_count[t];
    s[t] = v;
    __syncthreads();
    for (int off = 1; off < 256; off <<= 1) {
        int u = (t >= off) ? s[t - off] : 0;
        __syncthreads();
        s[t] += u;
        __syncthreads();
    }
    int excl = s[t] - v;
    if (t < nbuckets) { bucket_off[t] = excl; bucket_cursor[t] = excl; }
    if (t == 255) { bucket_off[nbuckets] = s[255]; rowptr[n] = s[255]; }
}

// A2: scatter (src,tgt) into per-bucket regions of tmp (block-run reservation).
__global__ __launch_bounds__(256) void bucketA2_kernel(const int* __restrict__ ei, int E,
                                                       int* __restrict__ bucket_cursor, int2* __restrict__ tmp) {
    __shared__ int hist[256], lbase[256], lcur[256];
    int t = threadIdx.x;
    hist[t] = 0; lcur[t] = 0;
    __syncthreads();
    int e0 = blockIdx.x * ACHUNK;
    int e1 = e0 + ACHUNK; if (e1 > E) e1 = E;
    for (int e = e0 + t; e < e1; e += 256)
        atomicAdd(&hist[ei[E + e] >> ABITS], 1);
    __syncthreads();
    int h = hist[t];
    if (h) lbase[t] = atomicAdd(&bucket_cursor[t], h);
    __syncthreads();
    for (int e = e0 + t; e < e1; e += 256) {
        int r = ei[e], c = ei[E + e];
        int b = c >> ABITS;
        int l = atomicAdd(&lcur[b], 1);
        tmp[lbase[b] + l] = make_int2(r, c);
    }
}

// B (merged): per bucket — stage edges in LDS, count degrees (LDS atomics),
// scan, write rowptr + dinv, place src indices into csr. No cross-bucket data
// needed (weights factored out), so one kernel, tmp read once.
__global__ __launch_bounds__(256) void bucketB_kernel(const int2* __restrict__ tmp,
                                                      const int* __restrict__ bucket_off,
                                                      int* __restrict__ rowptr, float* __restrict__ dinv,
                                                      int* __restrict__ csr, int n) {
    __shared__ int2 edg[BMAX];    // 64 KB
    __shared__ int cnt[512];
    __shared__ int ps[256];
    __shared__ int lrp[512];
    int b = blockIdx.x, t = threadIdx.x;
    int n0 = b << ABITS;
    int cntN = n - n0; if (cntN > 512) cntN = 512;
    int start = bucket_off[b], end = bucket_off[b + 1];
    int ne = end - start;
    bool inlds = ne <= BMAX;
    cnt[t] = 0; cnt[t + 256] = 0;
    if (inlds)
        for (int idx = t; idx < ne; idx += 256) edg[idx] = tmp[start + idx];
    __syncthreads();
    for (int idx = t; idx < ne; idx += 256) {
        int dst = inlds ? edg[idx].y : tmp[start + idx].y;
        atomicAdd(&cnt[dst - n0], 1);
    }
    __syncthreads();
    int c0 = cnt[2 * t], c1 = cnt[2 * t + 1];
    int s = c0 + c1;
    ps[t] = s;
    __syncthreads();
    for (int off = 1; off < 256; off <<= 1) {
        int u = (t >= off) ? ps[t - off] : 0;
        __syncthreads();
        ps[t] += u;
        __syncthreads();
    }
    int excl = ps[t] - s;
    if (2 * t < cntN) {
        lrp[2 * t] = start + excl;
        rowptr[n0 + 2 * t] = start + excl;
        dinv[n0 + 2 * t] = rsqrtf((float)(c0 + 1));
    }
    if (2 * t + 1 < cntN) {
        lrp[2 * t + 1] = start + excl + c0;
        rowptr[n0 + 2 * t + 1] = start + excl + c0;
        dinv[n0 + 2 * t + 1] = rsqrtf((float)(c1 + 1));
    }
    cnt[2 * t] = 0; cnt[2 * t + 1] = 0;   // reuse as cursors
    __syncthreads();
    for (int idx = t; idx < ne; idx += 256) {
        int2 st = inlds ? edg[idx] : tmp[start + idx];
        int lt = st.y - n0;
        int l = atomicAdd(&cnt[lt], 1);
        csr[lrp[lt] + l] = st.x;
    }
}

// ---------------- dense GEMM via MFMA: [n,K] @ [K,64] -> dinv[row] * result (f16) ----------------

template <int K, typename TIN>
__global__ __launch_bounds__(256) void gemm_kernel(const TIN* __restrict__ A, const float* __restrict__ W,
                                                   const float* __restrict__ dinv, __half* __restrict__ out, int n) {
    const int KP = K + 8;
    __shared__ _Float16 Ah[64 * (K + 8)];
    __shared__ _Float16 Wt[64 * (K + 8)];
    int tid = threadIdx.x;

    for (int idx = tid; idx < K * 64; idx += 256) {
        int k = idx >> 6, c = idx & 63;
        Wt[c * KP + k] = (_Float16)W[idx];
    }
    int row0 = blockIdx.x * 64;
    const TIN* Ab = A + (size_t)row0 * K;
    int limit = (n - row0) * K; if (limit > 64 * K) limit = 64 * K;

    if constexpr (sizeof(TIN) == 4) {   // float input
        for (int f = tid * 4; f < 64 * K; f += 1024) {
            float4 v = make_float4(0.f, 0.f, 0.f, 0.f);
            if (f + 3 < limit) {
                v = *(const float4*)((const float*)Ab + f);
            } else {
                if (f + 0 < limit) v.x = ((const float*)Ab)[f + 0];
                if (f + 1 < limit) v.y = ((const float*)Ab)[f + 1];
                if (f + 2 < limit) v.z = ((const float*)Ab)[f + 2];
            }
            int row = f / K, k = f % K;
            _Float16* dst = Ah + row * KP + k;
            dst[0] = (_Float16)v.x; dst[1] = (_Float16)v.y;
            dst[2] = (_Float16)v.z; dst[3] = (_Float16)v.w;
        }
    } else {                            // fp16 input: straight copy, no convert
        for (int f = tid * 8; f < 64 * K; f += 2048) {
            uint4 v = make_uint4(0, 0, 0, 0);
            if (f + 7 < limit) {
                v = *(const uint4*)((const __half*)Ab + f);
            } else {
                const __half* hp = (const __half*)Ab;
                __half tmp8[8];
                for (int j = 0; j < 8; ++j) tmp8[j] = (f + j < limit) ? hp[f + j] : __half(0);
                v = *(const uint4*)tmp8;
            }
            int row = f / K, k = f % K;
            *(uint4*)(Ah + row * KP + k) = v;
        }
    }
    __syncthreads();

    int w = tid >> 6, lane = tid & 63;
    int m = lane & 15, quad = lane >> 4;
    const _Float16* Aw = Ah + (size_t)(w * 16 + m) * KP + quad * 8;
    const _Float16* Bw = Wt + (size_t)m * KP + quad * 8;

    floatx4 acc0 = {0.f, 0.f, 0.f, 0.f}, acc1 = acc0, acc2 = acc0, acc3 = acc0;
    for (int k0 = 0; k0 < K; k0 += 32) {
        half8 a  = *(const half8*)(Aw + k0);
        half8 b0 = *(const half8*)(Bw + 0 * 16 * KP + k0);
        half8 b1 = *(const half8*)(Bw + 1 * 16 * KP + k0);
        half8 b2 = *(const half8*)(Bw + 2 * 16 * KP + k0);
        half8 b3 = *(const half8*)(Bw + 3 * 16 * KP + k0);
        acc0 = __builtin_amdgcn_mfma_f32_16x16x32_f16(a, b0, acc0, 0, 0, 0);
        acc1 = __builtin_amdgcn_mfma_f32_16x16x32_f16(a, b1, acc1, 0, 0, 0);
        acc2 = __builtin_amdgcn_mfma_f32_16x16x32_f16(a, b2, acc2, 0, 0, 0);
        acc3 = __builtin_amdgcn_mfma_f32_16x16x32_f16(a, b3, acc3, 0, 0, 0);
    }

    int rbase = row0 + w * 16 + quad * 4;
#pragma unroll
    for (int r = 0; r < 4; ++r) {
        int row = rbase + r;
        if (row < n) {
            float dv = dinv[row];   // fold source normalization into the row
            __half* o = out + (size_t)row * 64 + m;
            o[0]  = __float2half(acc0[r] * dv);
            o[16] = __float2half(acc1[r] * dv);
            o[32] = __float2half(acc2[r] * dv);
            o[48] = __float2half(acc3[r] * dv);
        }
    }
}

// ---------------- aggregation + bias + BN(eval) + ReLU (+classifier) ----------------
// Wave = 8 independent 8-lane groups, one node per group; lane owns a feature
// octet (16 B). ts rows are pre-scaled by dinv[src], so the inner loop is a pure
// gather+add; dinv[dst] applied once at the end. Unroll 8/4/2/1 tiers -> up to
// 64 gathers in flight per wave.

__device__ __forceinline__ void agg_add8(float4& lo, float4& hi, uint4 raw) {
    float2 p0 = __half22float2(*(const __half2*)&raw.x);
    float2 p1 = __half22float2(*(const __half2*)&raw.y);
    float2 p2 = __half22float2(*(const __half2*)&raw.z);
    float2 p3 = __half22float2(*(const __half2*)&raw.w);
    lo.x += p0.x; lo.y += p0.y; lo.z += p1.x; lo.w += p1.y;
    hi.x += p2.x; hi.y += p2.y; hi.z += p3.x; hi.w += p3.y;
}

template <bool FUSE_CLS>
__global__ __launch_bounds__(256) void agg_kernel(const __half* __restrict__ t, const float* __restrict__ dinv,
                                                  const int* __restrict__ rowptr, const int* __restrict__ csr,
                                                  const float* __restrict__ bias, const float* __restrict__ gamma,
                                                  const float* __restrict__ beta, const float* __restrict__ mean,
                                                  const float* __restrict__ var, __half* __restrict__ hout,
                                                  float* __restrict__ fout,
                                                  const float* __restrict__ cls_w, const float* __restrict__ cls_b,
                                                  int n) {
    int wave = threadIdx.x >> 6;
    int lane = threadIdx.x & 63;
    int g = lane >> 3;          // group 0..7 = node slot
    int fl = lane & 7;          // feature octet: features 8fl..8fl+7
    int i = (blockIdx.x * (blockDim.x >> 6) + wave) * 8 + g;
    if (i >= n) return;

    float4 lo = make_float4(0.f, 0.f, 0.f, 0.f);
    float4 hi = make_float4(0.f, 0.f, 0.f, 0.f);

    // self-loop: ts[i] (already dinv[i]-scaled)
    uint4 self = *(const uint4*)(t + (size_t)i * 64 + fl * 8);
    agg_add8(lo, hi, self);

    int e0 = rowptr[i], e1 = rowptr[i + 1];
    int e = e0;
    for (; e + 8 <= e1; e += 8) {
        int s0 = csr[e + 0], s1 = csr[e + 1], s2 = csr[e + 2], s3 = csr[e + 3];
        int s4 = csr[e + 4], s5 = csr[e + 5], s6 = csr[e + 6], s7 = csr[e + 7];
        uint4 r0 = *(const uint4*)(t + (size_t)s0 * 64 + fl * 8);
        uint4 r1 = *(const uint4*)(t + (size_t)s1 * 64 + fl * 8);
        uint4 r2 = *(const uint4*)(t + (size_t)s2 * 64 + fl * 8);
        uint4 r3 = *(const uint4*)(t + (size_t)s3 * 64 + fl * 8);
        uint4 r4 = *(const uint4*)(t + (size_t)s4 * 64 + fl * 8);
        uint4 r5 = *(const uint4*)(t + (size_t)s5 * 64 + fl * 8);
        uint4 r6 = *(const uint4*)(t + (size_t)s6 * 64 + fl * 8);
        uint4 r7 = *(const uint4*)(t + (size_t)s7 * 64 + fl * 8);
        agg_add8(lo, hi, r0); agg_add8(lo, hi, r1); agg_add8(lo, hi, r2); agg_add8(lo, hi, r3);
        agg_add8(lo, hi, r4); agg_add8(lo, hi, r5); agg_add8(lo, hi, r6); agg_add8(lo, hi, r7);
    }
    if (e + 4 <= e1) {
        int s0 = csr[e + 0], s1 = csr[e + 1], s2 = csr[e + 2], s3 = csr[e + 3];
        uint4 r0 = *(const uint4*)(t + (size_t)s0 * 64 + fl * 8);
        uint4 r1 = *(const uint4*)(t + (size_t)s1 * 64 + fl * 8);
        uint4 r2 = *(const uint4*)(t + (size_t)s2 * 64 + fl * 8);
        uint4 r3 = *(const uint4*)(t + (size_t)s3 * 64 + fl * 8);
        agg_add8(lo, hi, r0); agg_add8(lo, hi, r1); agg_add8(lo, hi, r2); agg_add8(lo, hi, r3);
        e += 4;
    }
    if (e + 2 <= e1) {
        int s0 = csr[e + 0], s1 = csr[e + 1];
        uint4 r0 = *(const uint4*)(t + (size_t)s0 * 64 + fl * 8);
        uint4 r1 = *(const uint4*)(t + (size_t)s1 * 64 + fl * 8);
        agg_add8(lo, hi, r0); agg_add8(lo, hi, r1);
        e += 2;
    }
    if (e < e1) {
        int s0 = csr[e];
        uint4 r0 = *(const uint4*)(t + (size_t)s0 * 64 + fl * 8);
        agg_add8(lo, hi, r0);
    }

    // destination normalization, then bias + BN(eval) + ReLU
    float di = dinv[i];
    lo.x *= di; lo.y *= di; lo.z *= di; lo.w *= di;
    hi.x *= di; hi.y *= di; hi.z *= di; hi.w *= di;

    float4 bbL = ((const float4*)bias)[2 * fl],  bbH = ((const float4*)bias)[2 * fl + 1];
    float4 ggL = ((const float4*)gamma)[2 * fl], ggH = ((const float4*)gamma)[2 * fl + 1];
    float4 beL = ((const float4*)beta)[2 * fl],  beH = ((const float4*)beta)[2 * fl + 1];
    float4 mmL = ((const float4*)mean)[2 * fl],  mmH = ((const float4*)mean)[2 * fl + 1];
    float4 vvL = ((const float4*)var)[2 * fl],   vvH = ((const float4*)var)[2 * fl + 1];
    float4 resL, resH;
    resL.x = fmaxf((lo.x + bbL.x - mmL.x) * (ggL.x * rsqrtf(vvL.x + EPS)) + beL.x, 0.f);
    resL.y = fmaxf((lo.y + bbL.y - mmL.y) * (ggL.y * rsqrtf(vvL.y + EPS)) + beL.y, 0.f);
    resL.z = fmaxf((lo.z + bbL.z - mmL.z) * (ggL.z * rsqrtf(vvL.z + EPS)) + beL.z, 0.f);
    resL.w = fmaxf((lo.w + bbL.w - mmL.w) * (ggL.w * rsqrtf(vvL.w + EPS)) + beL.w, 0.f);
    resH.x = fmaxf((hi.x + bbH.x - mmH.x) * (ggH.x * rsqrtf(vvH.x + EPS)) + beH.x, 0.f);
    resH.y = fmaxf((hi.y + bbH.y - mmH.y) * (ggH.y * rsqrtf(vvH.y + EPS)) + beH.y, 0.f);
    resH.z = fmaxf((hi.z + bbH.z - mmH.z) * (ggH.z * rsqrtf(vvH.z + EPS)) + beH.z, 0.f);
    resH.w = fmaxf((hi.w + bbH.w - mmH.w) * (ggH.w * rsqrtf(vvH.w + EPS)) + beH.w, 0.f);

    if (!FUSE_CLS) {
        // pack 8 halves, single 16 B store
        __half2 h0 = __floats2half2_rn(resL.x, resL.y);
        __half2 h1 = __floats2half2_rn(resL.z, resL.w);
        __half2 h2 = __floats2half2_rn(resH.x, resH.y);
        __half2 h3 = __floats2half2_rn(resH.z, resH.w);
        uint4 pk;
        pk.x = *(unsigned*)&h0; pk.y = *(unsigned*)&h1;
        pk.z = *(unsigned*)&h2; pk.w = *(unsigned*)&h3;
        ((uint4*)hout)[(size_t)i * 8 + fl] = pk;
    } else {
        const float4* cw = (const float4*)cls_w;
        float4 cwA = cw[4 * fl + 0], cwB = cw[4 * fl + 1], cwC = cw[4 * fl + 2], cwD = cw[4 * fl + 3];
        float c0 = resL.x * cwA.x + resL.y * cwA.z + resL.z * cwB.x + resL.w * cwB.z
                 + resH.x * cwC.x + resH.y * cwC.z + resH.z * cwD.x + resH.w * cwD.z;
        float c1 = resL.x * cwA.y + resL.y * cwA.w + resL.z * cwB.y + resL.w * cwB.w
                 + resH.x * cwC.y + resH.y * cwC.w + resH.z * cwD.y + resH.w * cwD.w;
        for (int off = 4; off > 0; off >>= 1) {
            c0 += __shfl_xor(c0, off);
            c1 += __shfl_xor(c1, off);
        }
        if (fl == 0) {
            fout[(size_t)i * 2 + 0] = c0 + cls_b[0];
            fout[(size_t)i * 2 + 1] = c1 + cls_b[1];
        }
    }
}

// ---------------- launch ----------------

extern "C" void kernel_launch(void* const* d_in, const int* in_sizes, int n_in,
                              void* d_out, int out_size, void* d_ws, size_t ws_size,
                              hipStream_t stream) {
    const float* x      = (const float*)d_in[0];
    const int*   ei     = (const int*)d_in[1];
    const float* w0     = (const float*)d_in[2];
    const float* w1     = (const float*)d_in[3];
    const float* w2     = (const float*)d_in[4];
    const float* biases = (const float*)d_in[5];
    const float* gamma  = (const float*)d_in[6];
    const float* beta   = (const float*)d_in[7];
    const float* rmean  = (const float*)d_in[8];
    const float* rvar   = (const float*)d_in[9];
    const float* cls_w  = (const float*)d_in[10];
    const float* cls_b  = (const float*)d_in[11];
    float* out = (float*)d_out;

    const int IN = 128, H = 64;
    const int N = in_sizes[0] / IN;   // 100000
    const int E = in_sizes[1] / 2;    // 1200000

    char* p = (char*)d_ws;
    auto carve = [&](size_t bytes) { void* q = (void*)p; p += (bytes + 255) & ~(size_t)255; return q; };
    float* dinv    = (float*)carve((size_t)N * 4);
    int*   rowptr  = (int*)carve((size_t)(N + 1) * 4);
    int2*  tmp     = (int2*)carve((size_t)E * 8);
    int*   csr     = (int*)carve((size_t)E * 4);
    int*   bucket_count  = (int*)carve((size_t)256 * 4);
    int*   bucket_off    = (int*)carve((size_t)257 * 4);
    int*   bucket_cursor = (int*)carve((size_t)256 * 4);
    __half* tbuf   = (__half*)carve((size_t)N * H * 2);
    __half* hbuf   = (__half*)carve((size_t)N * H * 2);

    int nbuckets = (N + (1 << ABITS) - 1) >> ABITS;   // 196 for N=100000
    int na = (E + ACHUNK - 1) / ACHUNK;               // 293

    hipMemsetAsync(bucket_count, 0, (size_t)256 * 4, stream);
    bucketA1_kernel<<<na, 256, 0, stream>>>(ei, E, bucket_count);
    bscan_kernel<<<1, 256, 0, stream>>>(bucket_count, bucket_off, bucket_cursor, rowptr, nbuckets, N);
    bucketA2_kernel<<<na, 256, 0, stream>>>(ei, E, bucket_cursor, tmp);
    bucketB_kernel<<<nbuckets, 256, 0, stream>>>(tmp, bucket_off, rowptr, dinv, csr, N);

    int gemm_grid = (N + 63) / 64;
    int agg_grid  = (N + 31) / 32;   // 32 nodes per block (4 waves x 8 groups)

    // layer 0
    gemm_kernel<128, float><<<gemm_grid, 256, 0, stream>>>(x, w0, dinv, tbuf, N);
    agg_kernel<false><<<agg_grid, 256, 0, stream>>>(tbuf, dinv, rowptr, csr,
        biases + 0, gamma + 0, beta + 0, rmean + 0, rvar + 0, hbuf, nullptr, nullptr, nullptr, N);
    // layer 1
    gemm_kernel<64, __half><<<gemm_grid, 256, 0, stream>>>(hbuf, w1, dinv, tbuf, N);
    agg_kernel<false><<<agg_grid, 256, 0, stream>>>(tbuf, dinv, rowptr, csr,
        biases + H, gamma + H, beta + H, rmean + H, rvar + H, hbuf, nullptr, nullptr, nullptr, N);
    // layer 2 + classifier
    gemm_kernel<64, __half><<<gemm_grid, 256, 0, stream>>>(hbuf, w2, dinv, tbuf, N);
    agg_kernel<true><<<agg_grid, 256, 0, stream>>>(tbuf, dinv, rowptr, csr,
        biases + 2 * H, gamma + 2 * H, beta + 2 * H, rmean + 2 * H, rvar + 2 * H, nullptr, out, cls_w, cls_b, N);
}